// Round 3
// baseline (431.167 us; speedup 1.0000x reference)
//
#include <hip/hip_runtime.h>
#include <cstdint>
#include <cstddef>

// B=4, S=2048, D=1024, U=1024 self-attention, fp32 in/out.
// R10 = R9 resubmit with hipMemsetAsync replaced by a zeroing kernel
//     (graph-capture de-risk; Guideline 9 whitelists only hipMemcpyAsync).
// R9: k_gemm256 (4-phase counted-vmcnt core) + LDS-staged vectorized
//     epilogues (EP_QK, EP_F32); PV on k_gemm256 split-K=2 + fp32 atomicAdd
//     (256 blocks = all CUs). V-proj stays on 128x128 4-blocks/CU kernel.

typedef unsigned short ushort_t;
typedef _Float16 half_t;
typedef __attribute__((ext_vector_type(8))) short short8;
typedef __attribute__((ext_vector_type(4))) float floatx4;

__device__ inline unsigned short h2u(half_t h) {
  union { half_t h; unsigned short u; } v; v.h = h; return v.u;
}

// async 16B global -> LDS (DMA). LDS dest = wave-uniform base + lane*16 (HW).
__device__ __forceinline__ void gload16(const half_t* g, half_t* l) {
  __builtin_amdgcn_global_load_lds(
      (const __attribute__((address_space(1))) unsigned int*)g,
      (__attribute__((address_space(3))) unsigned int*)l, 16, 0, 0);
}

#define BAR() asm volatile("s_barrier" ::: "memory")
#define LGKM0() asm volatile("s_waitcnt lgkmcnt(0)" ::: "memory")
#define VM6() asm volatile("s_waitcnt vmcnt(6)" ::: "memory")
#define VM0() asm volatile("s_waitcnt vmcnt(0)" ::: "memory")

// ---------- constants ----------
#define MX 8192       // B*S
#define KCAT 2048     // 2*D (fp16 2-term split-concatenated K dim)

// ws byte offsets (regions reused across phases; S overwrites xcat/wt)
#define XCAT_OFF 0UL                  // half [8192][2048] = 33554432 B
#define WT_OFF   50331648UL           // half 3 x [1024][2048] = 12582912 B
#define S_OFF    0UL                  // float [4][2048][2048] = 67108864 B
#define QCAT_OFF 69206016UL           // half [8192][2048]
#define KCAT_OFF 119537664UL          // half [8192][2048]
#define VT_OFF   169869312UL          // half [4][1024][2048] = 16777216 B
#define WS_NEED  186646528UL

// ---------- K0: zero the output (replaces hipMemsetAsync) ----------
__global__ __launch_bounds__(256) void k_zero(float* __restrict__ p, long long n4) {
  long long i = (long long)blockIdx.x * 256 + threadIdx.x;
  const floatx4 z = {0.f, 0.f, 0.f, 0.f};
  long long stride = (long long)gridDim.x * 256;
  for (; i < n4; i += stride) ((floatx4*)p)[i] = z;
}

// ---------- K1a: split inputs X -> Xcat = [xh | xl] (fp16) ----------
__global__ __launch_bounds__(256) void k_split_x(const float* __restrict__ X,
                                                 half_t* __restrict__ xcat) {
  long long i = (long long)blockIdx.x * 256 + threadIdx.x;  // over 8192*1024
  float x = X[i];
  half_t h = (half_t)x;
  half_t lo = (half_t)(x - (float)h);
  long long row = i >> 10;
  int col = (int)(i & 1023);
  half_t* r = xcat + row * KCAT;
  r[col] = h;
  r[col + 1024] = lo;
}

// ---------- K1b: transpose W -> WT_cat = [Wh | Wh] per weight ----------
__global__ __launch_bounds__(256) void k_split_wt(const float* __restrict__ Wq,
                                                  const float* __restrict__ Wk,
                                                  const float* __restrict__ Wv,
                                                  half_t* __restrict__ wt) {
  __shared__ float tile[64][65];
  const float* W = (blockIdx.z == 0) ? Wq : ((blockIdx.z == 1) ? Wk : Wv);
  half_t* out = wt + (size_t)blockIdx.z * 1024 * KCAT;
  int d0 = blockIdx.y * 64, u0 = blockIdx.x * 64;
  int t = threadIdx.x;
  int tr = t >> 6, tc = t & 63;
  for (int r = 0; r < 64; r += 4)
    tile[r + tr][tc] = W[(size_t)(d0 + r + tr) * 1024 + (u0 + tc)];
  __syncthreads();
  for (int r = 0; r < 64; r += 4) {
    int urow = r + tr, dcol = tc;
    float x = tile[dcol][urow];  // = WT[u0+urow][d0+dcol]
    half_t h = (half_t)x;
    half_t* o = out + (size_t)(u0 + urow) * KCAT + d0;
    o[dcol] = h;
    o[dcol + 1024] = h;
  }
}

enum { EP_F32 = 0, EP_QK = 1, EP_VT = 2, EP_ATOMIC = 3 };

// ---------- old 128x128 GEMM (kept for V-proj EP_VT: 4 blocks/CU) ----------
template <int MODE>
__global__ __launch_bounds__(256, 4) void k_gemm(
    const half_t* __restrict__ A, long long aBatch, int lda,
    const half_t* __restrict__ Bt, long long bBatch, int ldb,
    void* __restrict__ Cout, long long cBatch, int ldc, int K,
    half_t* __restrict__ CoutK) {
  __shared__ __align__(16) half_t As[128 * 64];
  __shared__ __align__(16) half_t Bs[128 * 64];
  const int t = threadIdx.x;
  const int z = blockIdx.z;
  A += (long long)z * aBatch;
  Bt += (long long)z * bBatch;
  const int m0 = blockIdx.y * 128, n0 = blockIdx.x * 128;

  const int w = t >> 6, l = t & 63;
  const int lr = l & 15, quad = l >> 4;
  const int wm = (w >> 1) * 64, wn = (w & 1) * 64;

  const floatx4 fz = {0.f, 0.f, 0.f, 0.f};
  floatx4 acc[4][4];
#pragma unroll
  for (int i = 0; i < 4; i++)
#pragma unroll
    for (int j = 0; j < 4; j++) acc[i][j] = fz;

  const half_t* Ap[4];
  const half_t* Bp[4];
  half_t* ldsA[4];
  half_t* ldsB[4];
#pragma unroll
  for (int s = 0; s < 4; s++) {
    int c = s * 256 + t;
    int row = c >> 3, gq = (c & 7) ^ ((c >> 3) & 7);
    Ap[s] = A + (long long)(m0 + row) * lda + gq * 8;
    Bp[s] = Bt + (long long)(n0 + row) * ldb + gq * 8;
    ldsA[s] = &As[(s * 256 + w * 64) * 8];
    ldsB[s] = &Bs[(s * 256 + w * 64) * 8];
  }

  const int p0 = quad ^ (lr & 7);
  const int p1 = (quad + 4) ^ (lr & 7);
  const int arow = (wm + lr) * 64, brow = (wn + lr) * 64;

  for (int kb = 0; kb < K; kb += 64) {
    __syncthreads();
#pragma unroll
    for (int s = 0; s < 4; s++) {
      gload16(Ap[s] + kb, ldsA[s]);
      gload16(Bp[s] + kb, ldsB[s]);
    }
    __syncthreads();
#pragma unroll
    for (int s = 0; s < 2; s++) {
      const int pp = s ? p1 : p0;
      short8 af[4], bfg[4];
#pragma unroll
      for (int j = 0; j < 4; j++) bfg[j] = *(const short8*)&Bs[brow + j * 1024 + pp * 8];
#pragma unroll
      for (int i = 0; i < 4; i++) af[i] = *(const short8*)&As[arow + i * 1024 + pp * 8];
#pragma unroll
      for (int i = 0; i < 4; i++)
#pragma unroll
        for (int j = 0; j < 4; j++)
          acc[i][j] = __builtin_amdgcn_mfma_f32_16x16x32_f16(af[i], bfg[j], acc[i][j], 0, 0, 0);
    }
  }

#pragma unroll
  for (int i = 0; i < 4; i++) {
#pragma unroll
    for (int j = 0; j < 4; j++) {
#pragma unroll
      for (int r = 0; r < 4; r++) {
        int grow = m0 + wm + i * 16 + quad * 4 + r;
        int gcol = n0 + wn + j * 16 + lr;
        float v = acc[i][j][r];
        if (MODE == EP_F32) {
          float* C = (float*)Cout + (long long)z * cBatch;
          C[(long long)grow * ldc + gcol] = v;
        } else if (MODE == EP_QK) {
          int sel = gcol >> 10;
          int ucol = gcol & 1023;
          half_t h = (half_t)v;
          if (sel == 0) {
            half_t* pq = (half_t*)Cout + (long long)grow * KCAT;
            pq[ucol] = h;
            pq[ucol + 1024] = (half_t)(v - (float)h);
          } else {
            half_t* pk = CoutK + (long long)grow * KCAT;
            pk[ucol] = h;
            pk[ucol + 1024] = h;
          }
        } else {  // EP_VT
          half_t* C = (half_t*)Cout;
          int b = grow >> 11, s = grow & 2047;
          C[((long long)b * 1024 + gcol) * 2048 + s] = (half_t)v;
        }
      }
    }
  }
}

// ---------- 256x256 GEMM, 4-phase counted-vmcnt schedule ----------
// Core unchanged from R8 (verified ledger). LDS-staged epilogues and
// EP_ATOMIC split-K mode (z = batch*2 + khalf, K-offset = khalf*1024).
template <int MODE>
__global__ __launch_bounds__(512, 2) void k_gemm256(
    const half_t* __restrict__ A, long long aBatch, int lda,
    const half_t* __restrict__ Bt, long long bBatch, int ldb,
    void* __restrict__ Cout, long long cBatch, int ldc, int K,
    half_t* __restrict__ CoutK) {
  __shared__ __align__(16) half_t LDS[65536];  // As=LDS[0:32768), Bs=[32768:)
  half_t* As = LDS;
  half_t* Bs = LDS + 32768;
  const int tid = threadIdx.x;
  const int z = blockIdx.z;
  int zb = z, kOff = 0;
  if (MODE == EP_ATOMIC) { zb = z >> 1; kOff = (z & 1) * 1024; }
  A += (long long)zb * aBatch + kOff;
  Bt += (long long)zb * bBatch + kOff;
  const int m0 = blockIdx.y * 256, n0 = blockIdx.x * 256;
  const int w = tid >> 6, l = tid & 63;
  const int lr = l & 15, quad = l >> 4;
  const int wm = w >> 2, wn = w & 3;

  const floatx4 fz = {0.f, 0.f, 0.f, 0.f};
  floatx4 acc[8][4];
#pragma unroll
  for (int i = 0; i < 8; i++)
#pragma unroll
    for (int j = 0; j < 4; j++) acc[i][j] = fz;

  // staging: chunk c in [0,1024) per k-half: row=c>>2, phys=c&3,
  // global chunk gq = (c&3)^((c>>3)&3). Thread stages c = tid and 512+tid.
  const int r0 = tid >> 2;
  const int gq0 = (tid & 3) ^ ((tid >> 3) & 3);
  const half_t* aS0 = A + (long long)(m0 + r0) * lda + gq0 * 8;
  const half_t* aS1 = aS0 + (long long)128 * lda;
  const half_t* bS0 = Bt + (long long)(n0 + r0) * ldb + gq0 * 8;
  const half_t* bS1 = bS0 + (long long)128 * ldb;
  const int wso = w << 9;  // wave-uniform LDS chunk base

  // frag read: row = Rbase + lr, phys chunk = quad ^ ((lr>>1)&3)
  const int swz = (quad ^ ((lr >> 1) & 3)) << 3;
  const int aBase = wm * 4096 + lr * 32 + swz;
  const int bBase = wn * 2048 + lr * 32 + swz;
  const int NT = K >> 6;

#define SA(BUF, KH, KOFF) do { half_t* d_ = &As[(BUF) * 16384 + (KH) * 8192 + wso]; \
    gload16(aS0 + (KOFF), d_); gload16(aS1 + (KOFF), d_ + 4096); } while (0)
#define SB(BUF, KH, KOFF) do { half_t* d_ = &Bs[(BUF) * 16384 + (KH) * 8192 + wso]; \
    gload16(bS0 + (KOFF), d_); gload16(bS1 + (KOFF), d_ + 4096); } while (0)
#define LDA4(OFF) { const half_t* ap_ = &As[(OFF)]; \
    af0 = *(const short8*)(ap_); af1 = *(const short8*)(ap_ + 512); \
    af2 = *(const short8*)(ap_ + 1024); af3 = *(const short8*)(ap_ + 1536); }
#define LDB4(OFF) { const half_t* bp_ = &Bs[(OFF)]; \
    bf0 = *(const short8*)(bp_); bf1 = *(const short8*)(bp_ + 512); \
    bf2 = *(const short8*)(bp_ + 1024); bf3 = *(const short8*)(bp_ + 1536); }
#define MFMA16(I0) do { \
    acc[(I0) + 0][0] = __builtin_amdgcn_mfma_f32_16x16x32_f16(af0, bf0, acc[(I0) + 0][0], 0, 0, 0); \
    acc[(I0) + 0][1] = __builtin_amdgcn_mfma_f32_16x16x32_f16(af0, bf1, acc[(I0) + 0][1], 0, 0, 0); \
    acc[(I0) + 0][2] = __builtin_amdgcn_mfma_f32_16x16x32_f16(af0, bf2, acc[(I0) + 0][2], 0, 0, 0); \
    acc[(I0) + 0][3] = __builtin_amdgcn_mfma_f32_16x16x32_f16(af0, bf3, acc[(I0) + 0][3], 0, 0, 0); \
    acc[(I0) + 1][0] = __builtin_amdgcn_mfma_f32_16x16x32_f16(af1, bf0, acc[(I0) + 1][0], 0, 0, 0); \
    acc[(I0) + 1][1] = __builtin_amdgcn_mfma_f32_16x16x32_f16(af1, bf1, acc[(I0) + 1][1], 0, 0, 0); \
    acc[(I0) + 1][2] = __builtin_amdgcn_mfma_f32_16x16x32_f16(af1, bf2, acc[(I0) + 1][2], 0, 0, 0); \
    acc[(I0) + 1][3] = __builtin_amdgcn_mfma_f32_16x16x32_f16(af1, bf3, acc[(I0) + 1][3], 0, 0, 0); \
    acc[(I0) + 2][0] = __builtin_amdgcn_mfma_f32_16x16x32_f16(af2, bf0, acc[(I0) + 2][0], 0, 0, 0); \
    acc[(I0) + 2][1] = __builtin_amdgcn_mfma_f32_16x16x32_f16(af2, bf1, acc[(I0) + 2][1], 0, 0, 0); \
    acc[(I0) + 2][2] = __builtin_amdgcn_mfma_f32_16x16x32_f16(af2, bf2, acc[(I0) + 2][2], 0, 0, 0); \
    acc[(I0) + 2][3] = __builtin_amdgcn_mfma_f32_16x16x32_f16(af2, bf3, acc[(I0) + 2][3], 0, 0, 0); \
    acc[(I0) + 3][0] = __builtin_amdgcn_mfma_f32_16x16x32_f16(af3, bf0, acc[(I0) + 3][0], 0, 0, 0); \
    acc[(I0) + 3][1] = __builtin_amdgcn_mfma_f32_16x16x32_f16(af3, bf1, acc[(I0) + 3][1], 0, 0, 0); \
    acc[(I0) + 3][2] = __builtin_amdgcn_mfma_f32_16x16x32_f16(af3, bf2, acc[(I0) + 3][2], 0, 0, 0); \
    acc[(I0) + 3][3] = __builtin_amdgcn_mfma_f32_16x16x32_f16(af3, bf3, acc[(I0) + 3][3], 0, 0, 0); \
  } while (0)

  // prologue: tile0 fully + tile1 {B-kh0, A-kh0, B-kh1}; last 3 stay in flight
  SB(0, 0, 0); SA(0, 0, 0); SB(0, 1, 32); SA(0, 1, 32);
  SB(1, 0, 64); SA(1, 0, 64); SB(1, 1, 96);
  VM6();
  BAR();

  for (int t = 0; t < NT; ++t) {
    const int buf = t & 1, nbuf = buf ^ 1;
    const int ab = buf * 16384;
    const int kb = t * 64;
    short8 af0, af1, af2, af3, bf0, bf1, bf2, bf3;

    // ---- P0: k-half0, M0-3 (+ B k-half0) ----
    LDA4(ab + aBase);
    LDB4(ab + bBase);
    if (t + 1 < NT) SA(nbuf, 1, kb + 96);  // (t+1).A-kh1
    BAR(); LGKM0();
    __builtin_amdgcn_s_setprio(1); MFMA16(0); __builtin_amdgcn_s_setprio(0);
    BAR();

    // ---- P1: k-half0, M4-7 (B regs reused) ----
    LDA4(ab + aBase + 2048);
    if (t + 2 < NT) SB(buf, 0, kb + 128);  // (t+2).B-kh0
    BAR(); LGKM0();
    __builtin_amdgcn_s_setprio(1); MFMA16(4); __builtin_amdgcn_s_setprio(0);
    BAR();

    // ---- P2: k-half1, M0-3 (+ B k-half1) ----
    LDA4(ab + 8192 + aBase);
    LDB4(ab + 8192 + bBase);
    if (t + 2 < NT) SA(buf, 0, kb + 128);  // (t+2).A-kh0
    BAR(); LGKM0();
    __builtin_amdgcn_s_setprio(1); MFMA16(0); __builtin_amdgcn_s_setprio(0);
    BAR();

    // ---- P3: k-half1, M4-7 ----
    LDA4(ab + 8192 + aBase + 2048);
    if (t + 2 < NT) SB(buf, 1, kb + 160);  // (t+2).B-kh1
    if (t < NT - 2) { VM6(); } else if (t == NT - 2) { VM0(); }  // tail drains
    BAR(); LGKM0();
    __builtin_amdgcn_s_setprio(1); MFMA16(4); __builtin_amdgcn_s_setprio(0);
    BAR();
  }

  // ================= epilogue =================
  // All waves past final MFMA (in-wave lgkm waits precede the MFMAs). One
  // barrier, then each wave uses its private 16 KB LDS slice -- wave-local
  // ds ordering needs no further barriers.
  BAR();
  half_t* wreg = &LDS[w * 8192];  // 16 KB per wave

  if (MODE == EP_QK) {
    // sel uniform per block (256-wide tile within one 1024 half)
    const int sel = n0 >> 10;
    const int ncol0 = (n0 & 1023) + wn * 64;
    half_t* dbase = (sel == 0) ? (half_t*)Cout : CoutK;
    const long long rb = (long long)(m0 + wm * 128);
#pragma unroll
    for (int round = 0; round < 2; ++round) {
      // write phase: fp16 [128 rows][8 chunks-of-8, XOR(row&7) swizzled]
#pragma unroll
      for (int i = 0; i < 8; i++)
#pragma unroll
        for (int j = 0; j < 4; j++)
#pragma unroll
          for (int r = 0; r < 4; r++) {
            int row = i * 16 + quad * 4 + r;
            int col = j * 16 + lr;
            float v = acc[i][j][r];
            half_t hv = (half_t)v;
            half_t val = (round == 0) ? hv
                         : (sel == 0 ? (half_t)(v - (float)hv) : hv);
            wreg[row * 64 + (((col >> 3) ^ (row & 7)) << 3) + (col & 7)] = val;
          }
      // read-back + coalesced 16B stores
#pragma unroll
      for (int k2 = 0; k2 < 16; ++k2) {
        int cid = l + 64 * k2;  // 1024 chunks of 16B
        int row = cid >> 3, q = cid & 7;
        short8 vv = *(const short8*)&wreg[row * 64 + ((q ^ (row & 7)) << 3)];
        half_t* dst = dbase + (rb + row) * KCAT + ncol0 + q * 8 + round * 1024;
        *(short8*)dst = vv;
      }
    }
  } else if (MODE == EP_F32) {
    float* wreg32 = (float*)wreg;  // 4096 floats = 16 KB
    float* C = (float*)Cout + (long long)zb * cBatch;
#pragma unroll
    for (int hh = 0; hh < 2; ++hh) {  // row halves 0-63 / 64-127
#pragma unroll
      for (int i2 = 0; i2 < 4; i2++)
#pragma unroll
        for (int j = 0; j < 4; j++)
#pragma unroll
          for (int r = 0; r < 4; r++) {
            int i = hh * 4 + i2;
            int row64 = i2 * 16 + quad * 4 + r;  // 0..63
            int col = j * 16 + lr;               // 0..63 floats
            int c4 = col >> 2;                   // 16 chunks of 16B
            wreg32[row64 * 64 + ((c4 ^ (row64 & 7)) << 2) + (col & 3)] =
                acc[i][j][r];
          }
      long long rbase = (long long)(m0 + wm * 128 + hh * 64);
#pragma unroll
      for (int k2 = 0; k2 < 16; ++k2) {
        int cid = l + 64 * k2;  // 1024 chunks of 16B
        int row64 = cid >> 4, q = cid & 15;
        floatx4 vv = *(const floatx4*)&wreg32[row64 * 64 + ((q ^ (row64 & 7)) << 2)];
        float* dst = C + (rbase + row64) * ldc + n0 + wn * 64 + q * 4;
        *(floatx4*)dst = vv;
      }
    }
  } else {  // EP_ATOMIC: split-K partial accumulate into pre-zeroed fp32 out
    float* C = (float*)Cout + (long long)zb * cBatch;
#pragma unroll
    for (int i = 0; i < 8; i++)
#pragma unroll
      for (int j = 0; j < 4; j++)
#pragma unroll
        for (int r = 0; r < 4; r++) {
          int grow = m0 + wm * 128 + i * 16 + quad * 4 + r;
          int gcol = n0 + wn * 64 + j * 16 + lr;
          atomicAdd(&C[(long long)grow * ldc + gcol], acc[i][j][r]);
        }
  }
#undef SA
#undef SB
#undef LDA4
#undef LDB4
#undef MFMA16
}

// ---------- softmax, in place: S row (fp32[2048]) -> P row (fp16[2048]) ----------
__global__ __launch_bounds__(256) void k_softmax(float* __restrict__ Sbuf) {
  long long row = blockIdx.x;  // 0..8191
  float* p = Sbuf + row * 2048;
  int t = threadIdx.x;
  float4 v0 = ((const float4*)p)[t];
  float4 v1 = ((const float4*)p)[t + 256];
  float m = fmaxf(fmaxf(fmaxf(v0.x, v0.y), fmaxf(v0.z, v0.w)),
                  fmaxf(fmaxf(v1.x, v1.y), fmaxf(v1.z, v1.w)));
  for (int off = 32; off; off >>= 1) m = fmaxf(m, __shfl_xor(m, off));
  __shared__ float red[8];
  int wv = t >> 6, ln = t & 63;
  if (ln == 0) red[wv] = m;
  __syncthreads();
  m = fmaxf(fmaxf(red[0], red[1]), fmaxf(red[2], red[3]));
  float e0 = __expf(v0.x - m), e1 = __expf(v0.y - m), e2 = __expf(v0.z - m), e3 = __expf(v0.w - m);
  float e4 = __expf(v1.x - m), e5 = __expf(v1.y - m), e6 = __expf(v1.z - m), e7 = __expf(v1.w - m);
  float s = ((e0 + e1) + (e2 + e3)) + ((e4 + e5) + (e6 + e7));
  for (int off = 32; off; off >>= 1) s += __shfl_xor(s, off);
  if (ln == 0) red[4 + wv] = s;
  __syncthreads();
  s = (red[4] + red[5]) + (red[6] + red[7]);
  float inv = 1.0f / s;
  uint2 w0, w1;
  w0.x = (unsigned)h2u((half_t)(e0 * inv)) | ((unsigned)h2u((half_t)(e1 * inv)) << 16);
  w0.y = (unsigned)h2u((half_t)(e2 * inv)) | ((unsigned)h2u((half_t)(e3 * inv)) << 16);
  w1.x = (unsigned)h2u((half_t)(e4 * inv)) | ((unsigned)h2u((half_t)(e5 * inv)) << 16);
  w1.y = (unsigned)h2u((half_t)(e6 * inv)) | ((unsigned)h2u((half_t)(e7 * inv)) << 16);
  ((uint2*)p)[t] = w0;
  ((uint2*)p)[t + 256] = w1;
}

// ---------- host launch ----------
extern "C" void kernel_launch(void* const* d_in, const int* in_sizes, int n_in,
                              void* d_out, int out_size, void* d_ws, size_t ws_size,
                              hipStream_t stream) {
  (void)in_sizes; (void)n_in; (void)out_size;
  if (ws_size < WS_NEED) return;  // output stays poisoned -> visible failure

  const float* X = (const float*)d_in[0];
  const float* Wq = (const float*)d_in[1];
  const float* Wk = (const float*)d_in[2];
  const float* Wv = (const float*)d_in[3];
  char* ws = (char*)d_ws;
  half_t* xcat = (half_t*)(ws + XCAT_OFF);
  half_t* wt = (half_t*)(ws + WT_OFF);
  float* Sbuf = (float*)(ws + S_OFF);
  half_t* qcat = (half_t*)(ws + QCAT_OFF);
  half_t* kcat = (half_t*)(ws + KCAT_OFF);
  half_t* vt = (half_t*)(ws + VT_OFF);
  float* out = (float*)d_out;

  // 0. zero output for split-K accumulate (runs while projections proceed? no
  //    stream-ordered, but it's ~7 us and overlapped with nothing else anyway)
  k_zero<<<dim3(1024), dim3(256), 0, stream>>>(out, (long long)MX * 1024 / 4);

  // 1. split X and W (fp16)
  k_split_x<<<dim3(MX * 1024 / 256), dim3(256), 0, stream>>>(X, xcat);
  k_split_wt<<<dim3(16, 16, 3), dim3(256), 0, stream>>>(Wq, Wk, Wv, wt);

  // 2a. fused QK projection: M=8192, N=2048 (Wq|Wk), K=2048 (2-term)
  k_gemm256<EP_QK><<<dim3(8, 32, 1), dim3(512), 0, stream>>>(
      xcat, 0LL, KCAT, wt, 0LL, KCAT, qcat, 0LL, 0, KCAT, kcat);

  // 2b. V projection: M=8192, N=1024, K=1024 (1-term) -- 128^2, 4 blocks/CU
  k_gemm<EP_VT><<<dim3(8, 64, 1), dim3(256), 0, stream>>>(
      xcat, 0LL, KCAT, wt + 2 * 1024 * KCAT, 0LL, KCAT, vt, 0LL, 0, 1024, nullptr);

  // 3. scores S = Q K^T (fp16 2-term), fp32 out: per batch M=N=2048
  k_gemm256<EP_F32><<<dim3(8, 8, 4), dim3(512), 0, stream>>>(
      qcat, (long long)2048 * KCAT, KCAT, kcat, (long long)2048 * KCAT, KCAT,
      Sbuf, (long long)2048 * 2048, 2048, KCAT, nullptr);

  // 4. softmax in place (fp32 row -> fp16 row; row stride becomes 4096 halves)
  k_softmax<<<dim3(8192), dim3(256), 0, stream>>>(Sbuf);

  // 5. O = P V, split-K=2: z = batch*2 + khalf, K=1024 each, atomicAdd fp32.
  //    grid (4,8,8) = 256 blocks -> every CU busy (old path: 2 blocks/CU).
  k_gemm256<EP_ATOMIC><<<dim3(4, 8, 8), dim3(512), 0, stream>>>(
      (const half_t*)Sbuf, (long long)2048 * 4096, 4096,
      vt, (long long)1024 * 2048, 2048,
      out, (long long)2048 * 1024, 1024, 1024, nullptr);
}

// Round 4
// 359.612 us; speedup vs baseline: 1.1990x; 1.1990x over previous
//
#include <hip/hip_runtime.h>
#include <cstdint>
#include <cstddef>

// B=4, S=2048, D=1024, U=1024 self-attention, fp32 in/out.
// R11 = R8 core (known 336.7 us) + two narrow deltas:
//   (1) EP_QK epilogue: interleaved qcat/kcat pair layout -> packed uint
//       stores (128 dword stores vs 256 short stores; 64B coalescing).
//       Scores GEMM is k-permutation-invariant (same perm on A and B).
//   (2) PV: split-K=2 on the old 128^2 kernel (EP_PART, deterministic
//       partials into dead qcat/kcat region) + add kernel. 1024 blocks =
//       4/CU vs old 2/CU (424 TF cliff).
// R10's LDS-staged epilogues REVERTED (post-mortem: -51us on EP_QK,
// VGPR 96->128, MfmaUtil 33.7->20; K-loop codegen perturbation).

typedef unsigned short ushort_t;
typedef _Float16 half_t;
typedef __attribute__((ext_vector_type(8))) short short8;
typedef __attribute__((ext_vector_type(4))) float floatx4;

__device__ inline unsigned short h2u(half_t h) {
  union { half_t h; unsigned short u; } v; v.h = h; return v.u;
}

// async 16B global -> LDS (DMA). LDS dest = wave-uniform base + lane*16 (HW).
__device__ __forceinline__ void gload16(const half_t* g, half_t* l) {
  __builtin_amdgcn_global_load_lds(
      (const __attribute__((address_space(1))) unsigned int*)g,
      (__attribute__((address_space(3))) unsigned int*)l, 16, 0, 0);
}

#define BAR() asm volatile("s_barrier" ::: "memory")
#define LGKM0() asm volatile("s_waitcnt lgkmcnt(0)" ::: "memory")
#define VM6() asm volatile("s_waitcnt vmcnt(6)" ::: "memory")
#define VM0() asm volatile("s_waitcnt vmcnt(0)" ::: "memory")

// ---------- constants ----------
#define MX 8192       // B*S
#define KCAT 2048     // 2*D (fp16 2-term split-concatenated K dim)

// ws byte offsets (regions reused across phases; S overwrites xcat/wt;
// PV partials overwrite qcat+kcat)
#define XCAT_OFF 0UL                  // half [8192][2048] = 33554432 B
#define WT_OFF   50331648UL           // half 3 x [1024][2048] = 12582912 B
#define S_OFF    0UL                  // float [4][2048][2048] = 67108864 B
#define QCAT_OFF 69206016UL           // half [8192][2048]
#define KCAT_OFF 119537664UL          // half [8192][2048]
#define PART_OFF QCAT_OFF             // float 2 x [8192][1024] = 67108864 B
#define VT_OFF   169869312UL          // half [4][1024][2048] = 16777216 B
#define WS_NEED  186646528UL

// ---------- K1a: split inputs X -> Xcat = [xh | xl] (fp16) ----------
__global__ __launch_bounds__(256) void k_split_x(const float* __restrict__ X,
                                                 half_t* __restrict__ xcat) {
  long long i = (long long)blockIdx.x * 256 + threadIdx.x;  // over 8192*1024
  float x = X[i];
  half_t h = (half_t)x;
  half_t lo = (half_t)(x - (float)h);
  long long row = i >> 10;
  int col = (int)(i & 1023);
  half_t* r = xcat + row * KCAT;
  r[col] = h;
  r[col + 1024] = lo;
}

// ---------- K1b: transpose W -> WT_cat = [Wh | Wh] per weight ----------
__global__ __launch_bounds__(256) void k_split_wt(const float* __restrict__ Wq,
                                                  const float* __restrict__ Wk,
                                                  const float* __restrict__ Wv,
                                                  half_t* __restrict__ wt) {
  __shared__ float tile[64][65];
  const float* W = (blockIdx.z == 0) ? Wq : ((blockIdx.z == 1) ? Wk : Wv);
  half_t* out = wt + (size_t)blockIdx.z * 1024 * KCAT;
  int d0 = blockIdx.y * 64, u0 = blockIdx.x * 64;
  int t = threadIdx.x;
  int tr = t >> 6, tc = t & 63;
  for (int r = 0; r < 64; r += 4)
    tile[r + tr][tc] = W[(size_t)(d0 + r + tr) * 1024 + (u0 + tc)];
  __syncthreads();
  for (int r = 0; r < 64; r += 4) {
    int urow = r + tr, dcol = tc;
    float x = tile[dcol][urow];  // = WT[u0+urow][d0+dcol]
    half_t h = (half_t)x;
    half_t* o = out + (size_t)(u0 + urow) * KCAT + d0;
    o[dcol] = h;
    o[dcol + 1024] = h;
  }
}

// ---------- K6: out = partial0 + partial1 (PV split-K reduce) ----------
__global__ __launch_bounds__(256) void k_addout(const float* __restrict__ part,
                                                float* __restrict__ out,
                                                long long n4) {
  long long i = (long long)blockIdx.x * 256 + threadIdx.x;
  long long stride = (long long)gridDim.x * 256;
  const floatx4* p0 = (const floatx4*)part;
  const floatx4* p1 = (const floatx4*)(part + (long long)MX * 1024);
  floatx4* o4 = (floatx4*)out;
  for (; i < n4; i += stride) {
    floatx4 a = p0[i];
    floatx4 b = p1[i];
    o4[i] = a + b;
  }
}

enum { EP_F32 = 0, EP_QK = 1, EP_VT = 2, EP_PART = 3 };

// ---------- old 128x128 GEMM (V-proj EP_VT; PV split-K EP_PART) ----------
template <int MODE>
__global__ __launch_bounds__(256, 4) void k_gemm(
    const half_t* __restrict__ A, long long aBatch, int lda,
    const half_t* __restrict__ Bt, long long bBatch, int ldb,
    void* __restrict__ Cout, long long cBatch, int ldc, int K,
    half_t* __restrict__ CoutK) {
  __shared__ __align__(16) half_t As[128 * 64];
  __shared__ __align__(16) half_t Bs[128 * 64];
  const int t = threadIdx.x;
  const int z = blockIdx.z;
  int zb = z, kOff = 0;
  if (MODE == EP_PART) { zb = z >> 1; kOff = (z & 1) << 10; }
  A += (long long)zb * aBatch + kOff;
  Bt += (long long)zb * bBatch + kOff;
  const int m0 = blockIdx.y * 128, n0 = blockIdx.x * 128;

  const int w = t >> 6, l = t & 63;
  const int lr = l & 15, quad = l >> 4;
  const int wm = (w >> 1) * 64, wn = (w & 1) * 64;

  const floatx4 fz = {0.f, 0.f, 0.f, 0.f};
  floatx4 acc[4][4];
#pragma unroll
  for (int i = 0; i < 4; i++)
#pragma unroll
    for (int j = 0; j < 4; j++) acc[i][j] = fz;

  const half_t* Ap[4];
  const half_t* Bp[4];
  half_t* ldsA[4];
  half_t* ldsB[4];
#pragma unroll
  for (int s = 0; s < 4; s++) {
    int c = s * 256 + t;
    int row = c >> 3, gq = (c & 7) ^ ((c >> 3) & 7);
    Ap[s] = A + (long long)(m0 + row) * lda + gq * 8;
    Bp[s] = Bt + (long long)(n0 + row) * ldb + gq * 8;
    ldsA[s] = &As[(s * 256 + w * 64) * 8];
    ldsB[s] = &Bs[(s * 256 + w * 64) * 8];
  }

  const int p0 = quad ^ (lr & 7);
  const int p1 = (quad + 4) ^ (lr & 7);
  const int arow = (wm + lr) * 64, brow = (wn + lr) * 64;

  for (int kb = 0; kb < K; kb += 64) {
    __syncthreads();
#pragma unroll
    for (int s = 0; s < 4; s++) {
      gload16(Ap[s] + kb, ldsA[s]);
      gload16(Bp[s] + kb, ldsB[s]);
    }
    __syncthreads();
#pragma unroll
    for (int s = 0; s < 2; s++) {
      const int pp = s ? p1 : p0;
      short8 af[4], bfg[4];
#pragma unroll
      for (int j = 0; j < 4; j++) bfg[j] = *(const short8*)&Bs[brow + j * 1024 + pp * 8];
#pragma unroll
      for (int i = 0; i < 4; i++) af[i] = *(const short8*)&As[arow + i * 1024 + pp * 8];
#pragma unroll
      for (int i = 0; i < 4; i++)
#pragma unroll
        for (int j = 0; j < 4; j++)
          acc[i][j] = __builtin_amdgcn_mfma_f32_16x16x32_f16(af[i], bfg[j], acc[i][j], 0, 0, 0);
    }
  }

#pragma unroll
  for (int i = 0; i < 4; i++) {
#pragma unroll
    for (int j = 0; j < 4; j++) {
#pragma unroll
      for (int r = 0; r < 4; r++) {
        int grow = m0 + wm + i * 16 + quad * 4 + r;
        int gcol = n0 + wn + j * 16 + lr;
        float v = acc[i][j][r];
        if (MODE == EP_F32) {
          float* C = (float*)Cout + (long long)zb * cBatch;
          C[(long long)grow * ldc + gcol] = v;
        } else if (MODE == EP_PART) {
          // partial (z&1) of PV split-K, direct store
          float* C = (float*)Cout + (long long)(z & 1) * ((long long)MX * 1024) +
                     (long long)zb * cBatch;
          C[(long long)grow * ldc + gcol] = v;
        } else {  // EP_VT
          half_t* C = (half_t*)Cout;
          int b = grow >> 11, s = grow & 2047;
          C[((long long)b * 1024 + gcol) * 2048 + s] = (half_t)v;
        }
      }
    }
  }
}

// ---------- 256x256 GEMM, 4-phase counted-vmcnt schedule (R8 core) ----------
// 8 waves (2M x 4N), per-wave 128x64 output = acc[8][4] frags of 16x16x32.
// LDS per matrix: [dbuf:2][khalf:2][256 rows][32 halves] = 64 KiB; total 128.
// Phases per K-tile t (buf = t&1): P0 k0/M0-3+B0, P1 k0/M4-7, P2 k1/M0-3+B1,
// P3 k1/M4-7. Stage issues (ledger-verified): P0 -> (t+1).A-kh1,
// P1 -> (t+2).B-kh0, P2 -> (t+2).A-kh0, P3 -> (t+2).B-kh1 then vmcnt(6).
template <int MODE>
__global__ __launch_bounds__(512, 2) void k_gemm256(
    const half_t* __restrict__ A, long long aBatch, int lda,
    const half_t* __restrict__ Bt, long long bBatch, int ldb,
    void* __restrict__ Cout, long long cBatch, int ldc, int K,
    half_t* __restrict__ CoutK) {
  __shared__ __align__(16) half_t As[32768];  // [2][2][256*32]
  __shared__ __align__(16) half_t Bs[32768];
  const int tid = threadIdx.x;
  const int z = blockIdx.z;
  A += (long long)z * aBatch;
  Bt += (long long)z * bBatch;
  const int m0 = blockIdx.y * 256, n0 = blockIdx.x * 256;
  const int w = tid >> 6, l = tid & 63;
  const int lr = l & 15, quad = l >> 4;
  const int wm = w >> 2, wn = w & 3;

  const floatx4 fz = {0.f, 0.f, 0.f, 0.f};
  floatx4 acc[8][4];
#pragma unroll
  for (int i = 0; i < 8; i++)
#pragma unroll
    for (int j = 0; j < 4; j++) acc[i][j] = fz;

  // staging: chunk c in [0,1024) per k-half: row=c>>2, phys=c&3,
  // global chunk gq = (c&3)^((c>>3)&3). Thread stages c = tid and 512+tid.
  const int r0 = tid >> 2;
  const int gq0 = (tid & 3) ^ ((tid >> 3) & 3);
  const half_t* aS0 = A + (long long)(m0 + r0) * lda + gq0 * 8;
  const half_t* aS1 = aS0 + (long long)128 * lda;
  const half_t* bS0 = Bt + (long long)(n0 + r0) * ldb + gq0 * 8;
  const half_t* bS1 = bS0 + (long long)128 * ldb;
  const int wso = w << 9;  // wave-uniform LDS chunk base

  // frag read: row = Rbase + lr, phys chunk = quad ^ ((lr>>1)&3)
  const int swz = (quad ^ ((lr >> 1) & 3)) << 3;
  const int aBase = wm * 4096 + lr * 32 + swz;
  const int bBase = wn * 2048 + lr * 32 + swz;
  const int NT = K >> 6;

#define SA(BUF, KH, KOFF) do { half_t* d_ = &As[(BUF) * 16384 + (KH) * 8192 + wso]; \
    gload16(aS0 + (KOFF), d_); gload16(aS1 + (KOFF), d_ + 4096); } while (0)
#define SB(BUF, KH, KOFF) do { half_t* d_ = &Bs[(BUF) * 16384 + (KH) * 8192 + wso]; \
    gload16(bS0 + (KOFF), d_); gload16(bS1 + (KOFF), d_ + 4096); } while (0)
#define LDA4(OFF) { const half_t* ap_ = &As[(OFF)]; \
    af0 = *(const short8*)(ap_); af1 = *(const short8*)(ap_ + 512); \
    af2 = *(const short8*)(ap_ + 1024); af3 = *(const short8*)(ap_ + 1536); }
#define LDB4(OFF) { const half_t* bp_ = &Bs[(OFF)]; \
    bf0 = *(const short8*)(bp_); bf1 = *(const short8*)(bp_ + 512); \
    bf2 = *(const short8*)(bp_ + 1024); bf3 = *(const short8*)(bp_ + 1536); }
#define MFMA16(I0) do { \
    acc[(I0) + 0][0] = __builtin_amdgcn_mfma_f32_16x16x32_f16(af0, bf0, acc[(I0) + 0][0], 0, 0, 0); \
    acc[(I0) + 0][1] = __builtin_amdgcn_mfma_f32_16x16x32_f16(af0, bf1, acc[(I0) + 0][1], 0, 0, 0); \
    acc[(I0) + 0][2] = __builtin_amdgcn_mfma_f32_16x16x32_f16(af0, bf2, acc[(I0) + 0][2], 0, 0, 0); \
    acc[(I0) + 0][3] = __builtin_amdgcn_mfma_f32_16x16x32_f16(af0, bf3, acc[(I0) + 0][3], 0, 0, 0); \
    acc[(I0) + 1][0] = __builtin_amdgcn_mfma_f32_16x16x32_f16(af1, bf0, acc[(I0) + 1][0], 0, 0, 0); \
    acc[(I0) + 1][1] = __builtin_amdgcn_mfma_f32_16x16x32_f16(af1, bf1, acc[(I0) + 1][1], 0, 0, 0); \
    acc[(I0) + 1][2] = __builtin_amdgcn_mfma_f32_16x16x32_f16(af1, bf2, acc[(I0) + 1][2], 0, 0, 0); \
    acc[(I0) + 1][3] = __builtin_amdgcn_mfma_f32_16x16x32_f16(af1, bf3, acc[(I0) + 1][3], 0, 0, 0); \
    acc[(I0) + 2][0] = __builtin_amdgcn_mfma_f32_16x16x32_f16(af2, bf0, acc[(I0) + 2][0], 0, 0, 0); \
    acc[(I0) + 2][1] = __builtin_amdgcn_mfma_f32_16x16x32_f16(af2, bf1, acc[(I0) + 2][1], 0, 0, 0); \
    acc[(I0) + 2][2] = __builtin_amdgcn_mfma_f32_16x16x32_f16(af2, bf2, acc[(I0) + 2][2], 0, 0, 0); \
    acc[(I0) + 2][3] = __builtin_amdgcn_mfma_f32_16x16x32_f16(af2, bf3, acc[(I0) + 2][3], 0, 0, 0); \
    acc[(I0) + 3][0] = __builtin_amdgcn_mfma_f32_16x16x32_f16(af3, bf0, acc[(I0) + 3][0], 0, 0, 0); \
    acc[(I0) + 3][1] = __builtin_amdgcn_mfma_f32_16x16x32_f16(af3, bf1, acc[(I0) + 3][1], 0, 0, 0); \
    acc[(I0) + 3][2] = __builtin_amdgcn_mfma_f32_16x16x32_f16(af3, bf2, acc[(I0) + 3][2], 0, 0, 0); \
    acc[(I0) + 3][3] = __builtin_amdgcn_mfma_f32_16x16x32_f16(af3, bf3, acc[(I0) + 3][3], 0, 0, 0); \
  } while (0)

  // prologue: tile0 fully + tile1 {B-kh0, A-kh0, B-kh1}; last 3 stay in flight
  SB(0, 0, 0); SA(0, 0, 0); SB(0, 1, 32); SA(0, 1, 32);
  SB(1, 0, 64); SA(1, 0, 64); SB(1, 1, 96);
  VM6();
  BAR();

  for (int t = 0; t < NT; ++t) {
    const int buf = t & 1, nbuf = buf ^ 1;
    const int ab = buf * 16384;
    const int kb = t * 64;
    short8 af0, af1, af2, af3, bf0, bf1, bf2, bf3;

    // ---- P0: k-half0, M0-3 (+ B k-half0) ----
    LDA4(ab + aBase);
    LDB4(ab + bBase);
    if (t + 1 < NT) SA(nbuf, 1, kb + 96);  // (t+1).A-kh1
    BAR(); LGKM0();
    __builtin_amdgcn_s_setprio(1); MFMA16(0); __builtin_amdgcn_s_setprio(0);
    BAR();

    // ---- P1: k-half0, M4-7 (B regs reused) ----
    LDA4(ab + aBase + 2048);
    if (t + 2 < NT) SB(buf, 0, kb + 128);  // (t+2).B-kh0
    BAR(); LGKM0();
    __builtin_amdgcn_s_setprio(1); MFMA16(4); __builtin_amdgcn_s_setprio(0);
    BAR();

    // ---- P2: k-half1, M0-3 (+ B k-half1) ----
    LDA4(ab + 8192 + aBase);
    LDB4(ab + 8192 + bBase);
    if (t + 2 < NT) SA(buf, 0, kb + 128);  // (t+2).A-kh0
    BAR(); LGKM0();
    __builtin_amdgcn_s_setprio(1); MFMA16(0); __builtin_amdgcn_s_setprio(0);
    BAR();

    // ---- P3: k-half1, M4-7 ----
    LDA4(ab + 8192 + aBase + 2048);
    if (t + 2 < NT) SB(buf, 1, kb + 160);  // (t+2).B-kh1
    if (t < NT - 2) { VM6(); } else if (t == NT - 2) { VM0(); }  // tail drains
    BAR(); LGKM0();
    __builtin_amdgcn_s_setprio(1); MFMA16(4); __builtin_amdgcn_s_setprio(0);
    BAR();
  }

  // epilogue (direct stores, R8 style)
#pragma unroll
  for (int i = 0; i < 8; i++) {
#pragma unroll
    for (int j = 0; j < 4; j++) {
#pragma unroll
      for (int r = 0; r < 4; r++) {
        int grow = m0 + wm * 128 + i * 16 + quad * 4 + r;
        int gcol = n0 + wn * 64 + j * 16 + lr;
        float v = acc[i][j][r];
        if (MODE == EP_F32) {
          float* C = (float*)Cout + (long long)z * cBatch;
          C[(long long)grow * ldc + gcol] = v;
        } else {  // EP_QK, interleaved pair layout: row pos 2u,2u+1
          int sel = gcol >> 10;        // uniform per block (n0 multiple of 256)
          int ucol = gcol & 1023;
          half_t h = (half_t)v;
          unsigned hu = h2u(h);
          unsigned val;
          half_t* base;
          if (sel == 0) {  // Q: [qh, ql] pairs
            val = hu | ((unsigned)h2u((half_t)(v - (float)h)) << 16);
            base = (half_t*)Cout;
          } else {         // K: [kh, kh] pairs
            val = hu | (hu << 16);
            base = CoutK;
          }
          *(unsigned*)(base + (long long)grow * KCAT + 2 * ucol) = val;
        }
      }
    }
  }
#undef SA
#undef SB
#undef LDA4
#undef LDB4
#undef MFMA16
}

// ---------- softmax, in place: S row (fp32[2048]) -> P row (fp16[2048]) ----------
__global__ __launch_bounds__(256) void k_softmax(float* __restrict__ Sbuf) {
  long long row = blockIdx.x;  // 0..8191
  float* p = Sbuf + row * 2048;
  int t = threadIdx.x;
  float4 v0 = ((const float4*)p)[t];
  float4 v1 = ((const float4*)p)[t + 256];
  float m = fmaxf(fmaxf(fmaxf(v0.x, v0.y), fmaxf(v0.z, v0.w)),
                  fmaxf(fmaxf(v1.x, v1.y), fmaxf(v1.z, v1.w)));
  for (int off = 32; off; off >>= 1) m = fmaxf(m, __shfl_xor(m, off));
  __shared__ float red[8];
  int wv = t >> 6, ln = t & 63;
  if (ln == 0) red[wv] = m;
  __syncthreads();
  m = fmaxf(fmaxf(red[0], red[1]), fmaxf(red[2], red[3]));
  float e0 = __expf(v0.x - m), e1 = __expf(v0.y - m), e2 = __expf(v0.z - m), e3 = __expf(v0.w - m);
  float e4 = __expf(v1.x - m), e5 = __expf(v1.y - m), e6 = __expf(v1.z - m), e7 = __expf(v1.w - m);
  float s = ((e0 + e1) + (e2 + e3)) + ((e4 + e5) + (e6 + e7));
  for (int off = 32; off; off >>= 1) s += __shfl_xor(s, off);
  if (ln == 0) red[4 + wv] = s;
  __syncthreads();
  s = (red[4] + red[5]) + (red[6] + red[7]);
  float inv = 1.0f / s;
  uint2 w0, w1;
  w0.x = (unsigned)h2u((half_t)(e0 * inv)) | ((unsigned)h2u((half_t)(e1 * inv)) << 16);
  w0.y = (unsigned)h2u((half_t)(e2 * inv)) | ((unsigned)h2u((half_t)(e3 * inv)) << 16);
  w1.x = (unsigned)h2u((half_t)(e4 * inv)) | ((unsigned)h2u((half_t)(e5 * inv)) << 16);
  w1.y = (unsigned)h2u((half_t)(e6 * inv)) | ((unsigned)h2u((half_t)(e7 * inv)) << 16);
  ((uint2*)p)[t] = w0;
  ((uint2*)p)[t + 256] = w1;
}

// ---------- host launch ----------
extern "C" void kernel_launch(void* const* d_in, const int* in_sizes, int n_in,
                              void* d_out, int out_size, void* d_ws, size_t ws_size,
                              hipStream_t stream) {
  (void)in_sizes; (void)n_in; (void)out_size;
  if (ws_size < WS_NEED) return;  // output stays poisoned -> visible failure

  const float* X = (const float*)d_in[0];
  const float* Wq = (const float*)d_in[1];
  const float* Wk = (const float*)d_in[2];
  const float* Wv = (const float*)d_in[3];
  char* ws = (char*)d_ws;
  half_t* xcat = (half_t*)(ws + XCAT_OFF);
  half_t* wt = (half_t*)(ws + WT_OFF);
  float* Sbuf = (float*)(ws + S_OFF);
  half_t* qcat = (half_t*)(ws + QCAT_OFF);
  half_t* kcat = (half_t*)(ws + KCAT_OFF);
  float* part = (float*)(ws + PART_OFF);   // aliases qcat/kcat (dead at PV)
  half_t* vt = (half_t*)(ws + VT_OFF);
  float* out = (float*)d_out;

  // 1. split X and W (fp16)
  k_split_x<<<dim3(MX * 1024 / 256), dim3(256), 0, stream>>>(X, xcat);
  k_split_wt<<<dim3(16, 16, 3), dim3(256), 0, stream>>>(Wq, Wk, Wv, wt);

  // 2a. fused QK projection: M=8192, N=2048 (Wq|Wk), K=2048 (2-term)
  k_gemm256<EP_QK><<<dim3(8, 32, 1), dim3(512), 0, stream>>>(
      xcat, 0LL, KCAT, wt, 0LL, KCAT, qcat, 0LL, 0, KCAT, kcat);

  // 2b. V projection: M=8192, N=1024, K=1024 (1-term) -- 128^2, 4 blocks/CU
  k_gemm<EP_VT><<<dim3(8, 64, 1), dim3(256), 0, stream>>>(
      xcat, 0LL, KCAT, wt + 2 * 1024 * KCAT, 0LL, KCAT, vt, 0LL, 0, 1024, nullptr);

  // 3. scores S = Q K^T (fp16 2-term, interleaved k-layout on both sides)
  k_gemm256<EP_F32><<<dim3(8, 8, 4), dim3(512), 0, stream>>>(
      qcat, (long long)2048 * KCAT, KCAT, kcat, (long long)2048 * KCAT, KCAT,
      Sbuf, (long long)2048 * 2048, 2048, KCAT, nullptr);

  // 4. softmax in place (fp32 row -> fp16 row; row stride becomes 4096 halves)
  k_softmax<<<dim3(8192), dim3(256), 0, stream>>>(Sbuf);

  // 5. O = P V, split-K=2 deterministic: z = batch*2 + khalf, K=1024 each.
  //    1024 blocks = 4/CU (old path was 512 blocks = 2/CU, 424 TF).
  k_gemm<EP_PART><<<dim3(8, 16, 8), dim3(256), 0, stream>>>(
      (const half_t*)Sbuf, (long long)2048 * 4096, 4096,
      vt, (long long)1024 * 2048, 2048,
      part, (long long)2048 * 1024, 1024, 1024, nullptr);

  // 6. out = part0 + part1
  k_addout<<<dim3(2048), dim3(256), 0, stream>>>(part, out,
                                                 (long long)MX * 1024 / 4);
}

// Round 5
// 318.310 us; speedup vs baseline: 1.3546x; 1.1298x over previous
//
#include <hip/hip_runtime.h>
#include <cstdint>
#include <cstddef>

// B=4, S=2048, D=1024, U=1024 self-attention, fp32 in/out.
// R12 = R8 pipeline (known-good) + R11's verified packed EP_QK epilogue
//       (-3.5us) + XCD-aware bijective rectangle swizzle on all GEMMs.
// PV split-K REVERTED (post-mortem: EP_PART+addout ~107us vs 81; partial
// traffic + halved per-block K ate the occupancy gain).
// Swizzle mechanism: linear dispatch puts same blockIdx.x on each XCD ->
// every XCD streams the whole A matrix (EP_QK FETCH 135MB vs 40MB ideal).
// Rect remap gives each XCD a 4 x (ROWS/4) tile rectangle -> panel reuse.

typedef unsigned short ushort_t;
typedef _Float16 half_t;
typedef __attribute__((ext_vector_type(8))) short short8;
typedef __attribute__((ext_vector_type(4))) float floatx4;

__device__ inline unsigned short h2u(half_t h) {
  union { half_t h; unsigned short u; } v; v.h = h; return v.u;
}

// async 16B global -> LDS (DMA). LDS dest = wave-uniform base + lane*16 (HW).
__device__ __forceinline__ void gload16(const half_t* g, half_t* l) {
  __builtin_amdgcn_global_load_lds(
      (const __attribute__((address_space(1))) unsigned int*)g,
      (__attribute__((address_space(3))) unsigned int*)l, 16, 0, 0);
}

#define BAR() asm volatile("s_barrier" ::: "memory")
#define LGKM0() asm volatile("s_waitcnt lgkmcnt(0)" ::: "memory")
#define VM6() asm volatile("s_waitcnt vmcnt(6)" ::: "memory")
#define VM0() asm volatile("s_waitcnt vmcnt(0)" ::: "memory")

// ---------- constants ----------
#define MX 8192       // B*S
#define KCAT 2048     // 2*D (fp16 2-term split-concatenated K dim)

// ws byte offsets (regions reused across phases; S overwrites xcat/wt)
#define XCAT_OFF 0UL                  // half [8192][2048] = 33554432 B
#define WT_OFF   50331648UL           // half 3 x [1024][2048] = 12582912 B
#define S_OFF    0UL                  // float [4][2048][2048] = 67108864 B
#define QCAT_OFF 69206016UL           // half [8192][2048]
#define KCAT_OFF 119537664UL          // half [8192][2048]
#define VT_OFF   169869312UL          // half [4][1024][2048] = 16777216 B
#define WS_NEED  186646528UL

// XCD-aware bijective rectangle remap. Assumes XCD = linear_bid % 8
// (HW round-robin; perf-only assumption). Requires gridDim.x == 8 and
// gridDim.y*gridDim.z % 4 == 0 (true for all four GEMM launches).
// Each XCD gets a 4-wide x (ROWS/4)-tall rectangle of (bx, row) tiles.
#define XCD_REMAP(BX, BY, BZ)                                              \
  const int fbid_ = blockIdx.x + 8 * (blockIdx.y + gridDim.y * blockIdx.z); \
  const int xj_ = fbid_ & 7, xi_ = fbid_ >> 3;                              \
  const int BX = ((xj_ & 1) << 2) | (xi_ & 3);                              \
  const int nrow_ = (xj_ >> 1) * ((gridDim.y * gridDim.z) >> 2) + (xi_ >> 2);\
  const int BY = nrow_ % gridDim.y;                                         \
  const int BZ = nrow_ / gridDim.y;

// ---------- K1a: split inputs X -> Xcat = [xh | xl] (fp16) ----------
__global__ __launch_bounds__(256) void k_split_x(const float* __restrict__ X,
                                                 half_t* __restrict__ xcat) {
  long long i = (long long)blockIdx.x * 256 + threadIdx.x;  // over 8192*1024
  float x = X[i];
  half_t h = (half_t)x;
  half_t lo = (half_t)(x - (float)h);
  long long row = i >> 10;
  int col = (int)(i & 1023);
  half_t* r = xcat + row * KCAT;
  r[col] = h;
  r[col + 1024] = lo;
}

// ---------- K1b: transpose W -> WT_cat = [Wh | Wh] per weight ----------
__global__ __launch_bounds__(256) void k_split_wt(const float* __restrict__ Wq,
                                                  const float* __restrict__ Wk,
                                                  const float* __restrict__ Wv,
                                                  half_t* __restrict__ wt) {
  __shared__ float tile[64][65];
  const float* W = (blockIdx.z == 0) ? Wq : ((blockIdx.z == 1) ? Wk : Wv);
  half_t* out = wt + (size_t)blockIdx.z * 1024 * KCAT;
  int d0 = blockIdx.y * 64, u0 = blockIdx.x * 64;
  int t = threadIdx.x;
  int tr = t >> 6, tc = t & 63;
  for (int r = 0; r < 64; r += 4)
    tile[r + tr][tc] = W[(size_t)(d0 + r + tr) * 1024 + (u0 + tc)];
  __syncthreads();
  for (int r = 0; r < 64; r += 4) {
    int urow = r + tr, dcol = tc;
    float x = tile[dcol][urow];  // = WT[u0+urow][d0+dcol]
    half_t h = (half_t)x;
    half_t* o = out + (size_t)(u0 + urow) * KCAT + d0;
    o[dcol] = h;
    o[dcol + 1024] = h;
  }
}

enum { EP_F32 = 0, EP_QK = 1, EP_VT = 2 };

// ---------- old 128x128 GEMM (V-proj EP_VT; PV EP_F32) ----------
template <int MODE>
__global__ __launch_bounds__(256, 4) void k_gemm(
    const half_t* __restrict__ A, long long aBatch, int lda,
    const half_t* __restrict__ Bt, long long bBatch, int ldb,
    void* __restrict__ Cout, long long cBatch, int ldc, int K,
    half_t* __restrict__ CoutK) {
  __shared__ __align__(16) half_t As[128 * 64];
  __shared__ __align__(16) half_t Bs[128 * 64];
  const int t = threadIdx.x;
  XCD_REMAP(bx, by, z);
  A += (long long)z * aBatch;
  Bt += (long long)z * bBatch;
  const int m0 = by * 128, n0 = bx * 128;

  const int w = t >> 6, l = t & 63;
  const int lr = l & 15, quad = l >> 4;
  const int wm = (w >> 1) * 64, wn = (w & 1) * 64;

  const floatx4 fz = {0.f, 0.f, 0.f, 0.f};
  floatx4 acc[4][4];
#pragma unroll
  for (int i = 0; i < 4; i++)
#pragma unroll
    for (int j = 0; j < 4; j++) acc[i][j] = fz;

  const half_t* Ap[4];
  const half_t* Bp[4];
  half_t* ldsA[4];
  half_t* ldsB[4];
#pragma unroll
  for (int s = 0; s < 4; s++) {
    int c = s * 256 + t;
    int row = c >> 3, gq = (c & 7) ^ ((c >> 3) & 7);
    Ap[s] = A + (long long)(m0 + row) * lda + gq * 8;
    Bp[s] = Bt + (long long)(n0 + row) * ldb + gq * 8;
    ldsA[s] = &As[(s * 256 + w * 64) * 8];
    ldsB[s] = &Bs[(s * 256 + w * 64) * 8];
  }

  const int p0 = quad ^ (lr & 7);
  const int p1 = (quad + 4) ^ (lr & 7);
  const int arow = (wm + lr) * 64, brow = (wn + lr) * 64;

  for (int kb = 0; kb < K; kb += 64) {
    __syncthreads();
#pragma unroll
    for (int s = 0; s < 4; s++) {
      gload16(Ap[s] + kb, ldsA[s]);
      gload16(Bp[s] + kb, ldsB[s]);
    }
    __syncthreads();
#pragma unroll
    for (int s = 0; s < 2; s++) {
      const int pp = s ? p1 : p0;
      short8 af[4], bfg[4];
#pragma unroll
      for (int j = 0; j < 4; j++) bfg[j] = *(const short8*)&Bs[brow + j * 1024 + pp * 8];
#pragma unroll
      for (int i = 0; i < 4; i++) af[i] = *(const short8*)&As[arow + i * 1024 + pp * 8];
#pragma unroll
      for (int i = 0; i < 4; i++)
#pragma unroll
        for (int j = 0; j < 4; j++)
          acc[i][j] = __builtin_amdgcn_mfma_f32_16x16x32_f16(af[i], bfg[j], acc[i][j], 0, 0, 0);
    }
  }

#pragma unroll
  for (int i = 0; i < 4; i++) {
#pragma unroll
    for (int j = 0; j < 4; j++) {
#pragma unroll
      for (int r = 0; r < 4; r++) {
        int grow = m0 + wm + i * 16 + quad * 4 + r;
        int gcol = n0 + wn + j * 16 + lr;
        float v = acc[i][j][r];
        if (MODE == EP_F32) {
          float* C = (float*)Cout + (long long)z * cBatch;
          C[(long long)grow * ldc + gcol] = v;
        } else {  // EP_VT: V^T[b][u][s] = V[b*2048+s][u]
          half_t* C = (half_t*)Cout;
          int b = grow >> 11, s = grow & 2047;
          C[((long long)b * 1024 + gcol) * 2048 + s] = (half_t)v;
        }
      }
    }
  }
}

// ---------- 256x256 GEMM, 4-phase counted-vmcnt schedule (R8 core) ----------
// 8 waves (2M x 4N), per-wave 128x64 output = acc[8][4] frags of 16x16x32.
// LDS per matrix: [dbuf:2][khalf:2][256 rows][32 halves] = 64 KiB; total 128.
// Phases per K-tile t (buf = t&1): P0 k0/M0-3+B0, P1 k0/M4-7, P2 k1/M0-3+B1,
// P3 k1/M4-7. Stage issues (ledger-verified): P0 -> (t+1).A-kh1,
// P1 -> (t+2).B-kh0, P2 -> (t+2).A-kh0, P3 -> (t+2).B-kh1 then vmcnt(6).
template <int MODE>
__global__ __launch_bounds__(512, 2) void k_gemm256(
    const half_t* __restrict__ A, long long aBatch, int lda,
    const half_t* __restrict__ Bt, long long bBatch, int ldb,
    void* __restrict__ Cout, long long cBatch, int ldc, int K,
    half_t* __restrict__ CoutK) {
  __shared__ __align__(16) half_t As[32768];  // [2][2][256*32]
  __shared__ __align__(16) half_t Bs[32768];
  const int tid = threadIdx.x;
  XCD_REMAP(bx, by, z);
  A += (long long)z * aBatch;
  Bt += (long long)z * bBatch;
  const int m0 = by * 256, n0 = bx * 256;
  const int w = tid >> 6, l = tid & 63;
  const int lr = l & 15, quad = l >> 4;
  const int wm = w >> 2, wn = w & 3;

  const floatx4 fz = {0.f, 0.f, 0.f, 0.f};
  floatx4 acc[8][4];
#pragma unroll
  for (int i = 0; i < 8; i++)
#pragma unroll
    for (int j = 0; j < 4; j++) acc[i][j] = fz;

  // staging: chunk c in [0,1024) per k-half: row=c>>2, phys=c&3,
  // global chunk gq = (c&3)^((c>>3)&3). Thread stages c = tid and 512+tid.
  const int r0 = tid >> 2;
  const int gq0 = (tid & 3) ^ ((tid >> 3) & 3);
  const half_t* aS0 = A + (long long)(m0 + r0) * lda + gq0 * 8;
  const half_t* aS1 = aS0 + (long long)128 * lda;
  const half_t* bS0 = Bt + (long long)(n0 + r0) * ldb + gq0 * 8;
  const half_t* bS1 = bS0 + (long long)128 * ldb;
  const int wso = w << 9;  // wave-uniform LDS chunk base

  // frag read: row = Rbase + lr, phys chunk = quad ^ ((lr>>1)&3)
  const int swz = (quad ^ ((lr >> 1) & 3)) << 3;
  const int aBase = wm * 4096 + lr * 32 + swz;
  const int bBase = wn * 2048 + lr * 32 + swz;
  const int NT = K >> 6;

#define SA(BUF, KH, KOFF) do { half_t* d_ = &As[(BUF) * 16384 + (KH) * 8192 + wso]; \
    gload16(aS0 + (KOFF), d_); gload16(aS1 + (KOFF), d_ + 4096); } while (0)
#define SB(BUF, KH, KOFF) do { half_t* d_ = &Bs[(BUF) * 16384 + (KH) * 8192 + wso]; \
    gload16(bS0 + (KOFF), d_); gload16(bS1 + (KOFF), d_ + 4096); } while (0)
#define LDA4(OFF) { const half_t* ap_ = &As[(OFF)]; \
    af0 = *(const short8*)(ap_); af1 = *(const short8*)(ap_ + 512); \
    af2 = *(const short8*)(ap_ + 1024); af3 = *(const short8*)(ap_ + 1536); }
#define LDB4(OFF) { const half_t* bp_ = &Bs[(OFF)]; \
    bf0 = *(const short8*)(bp_); bf1 = *(const short8*)(bp_ + 512); \
    bf2 = *(const short8*)(bp_ + 1024); bf3 = *(const short8*)(bp_ + 1536); }
#define MFMA16(I0) do { \
    acc[(I0) + 0][0] = __builtin_amdgcn_mfma_f32_16x16x32_f16(af0, bf0, acc[(I0) + 0][0], 0, 0, 0); \
    acc[(I0) + 0][1] = __builtin_amdgcn_mfma_f32_16x16x32_f16(af0, bf1, acc[(I0) + 0][1], 0, 0, 0); \
    acc[(I0) + 0][2] = __builtin_amdgcn_mfma_f32_16x16x32_f16(af0, bf2, acc[(I0) + 0][2], 0, 0, 0); \
    acc[(I0) + 0][3] = __builtin_amdgcn_mfma_f32_16x16x32_f16(af0, bf3, acc[(I0) + 0][3], 0, 0, 0); \
    acc[(I0) + 1][0] = __builtin_amdgcn_mfma_f32_16x16x32_f16(af1, bf0, acc[(I0) + 1][0], 0, 0, 0); \
    acc[(I0) + 1][1] = __builtin_amdgcn_mfma_f32_16x16x32_f16(af1, bf1, acc[(I0) + 1][1], 0, 0, 0); \
    acc[(I0) + 1][2] = __builtin_amdgcn_mfma_f32_16x16x32_f16(af1, bf2, acc[(I0) + 1][2], 0, 0, 0); \
    acc[(I0) + 1][3] = __builtin_amdgcn_mfma_f32_16x16x32_f16(af1, bf3, acc[(I0) + 1][3], 0, 0, 0); \
    acc[(I0) + 2][0] = __builtin_amdgcn_mfma_f32_16x16x32_f16(af2, bf0, acc[(I0) + 2][0], 0, 0, 0); \
    acc[(I0) + 2][1] = __builtin_amdgcn_mfma_f32_16x16x32_f16(af2, bf1, acc[(I0) + 2][1], 0, 0, 0); \
    acc[(I0) + 2][2] = __builtin_amdgcn_mfma_f32_16x16x32_f16(af2, bf2, acc[(I0) + 2][2], 0, 0, 0); \
    acc[(I0) + 2][3] = __builtin_amdgcn_mfma_f32_16x16x32_f16(af2, bf3, acc[(I0) + 2][3], 0, 0, 0); \
    acc[(I0) + 3][0] = __builtin_amdgcn_mfma_f32_16x16x32_f16(af3, bf0, acc[(I0) + 3][0], 0, 0, 0); \
    acc[(I0) + 3][1] = __builtin_amdgcn_mfma_f32_16x16x32_f16(af3, bf1, acc[(I0) + 3][1], 0, 0, 0); \
    acc[(I0) + 3][2] = __builtin_amdgcn_mfma_f32_16x16x32_f16(af3, bf2, acc[(I0) + 3][2], 0, 0, 0); \
    acc[(I0) + 3][3] = __builtin_amdgcn_mfma_f32_16x16x32_f16(af3, bf3, acc[(I0) + 3][3], 0, 0, 0); \
  } while (0)

  // prologue: tile0 fully + tile1 {B-kh0, A-kh0, B-kh1}; last 3 stay in flight
  SB(0, 0, 0); SA(0, 0, 0); SB(0, 1, 32); SA(0, 1, 32);
  SB(1, 0, 64); SA(1, 0, 64); SB(1, 1, 96);
  VM6();
  BAR();

  for (int t = 0; t < NT; ++t) {
    const int buf = t & 1, nbuf = buf ^ 1;
    const int ab = buf * 16384;
    const int kb = t * 64;
    short8 af0, af1, af2, af3, bf0, bf1, bf2, bf3;

    // ---- P0: k-half0, M0-3 (+ B k-half0) ----
    LDA4(ab + aBase);
    LDB4(ab + bBase);
    if (t + 1 < NT) SA(nbuf, 1, kb + 96);  // (t+1).A-kh1
    BAR(); LGKM0();
    __builtin_amdgcn_s_setprio(1); MFMA16(0); __builtin_amdgcn_s_setprio(0);
    BAR();

    // ---- P1: k-half0, M4-7 (B regs reused) ----
    LDA4(ab + aBase + 2048);
    if (t + 2 < NT) SB(buf, 0, kb + 128);  // (t+2).B-kh0
    BAR(); LGKM0();
    __builtin_amdgcn_s_setprio(1); MFMA16(4); __builtin_amdgcn_s_setprio(0);
    BAR();

    // ---- P2: k-half1, M0-3 (+ B k-half1) ----
    LDA4(ab + 8192 + aBase);
    LDB4(ab + 8192 + bBase);
    if (t + 2 < NT) SA(buf, 0, kb + 128);  // (t+2).A-kh0
    BAR(); LGKM0();
    __builtin_amdgcn_s_setprio(1); MFMA16(0); __builtin_amdgcn_s_setprio(0);
    BAR();

    // ---- P3: k-half1, M4-7 ----
    LDA4(ab + 8192 + aBase + 2048);
    if (t + 2 < NT) SB(buf, 1, kb + 160);  // (t+2).B-kh1
    if (t < NT - 2) { VM6(); } else if (t == NT - 2) { VM0(); }  // tail drains
    BAR(); LGKM0();
    __builtin_amdgcn_s_setprio(1); MFMA16(4); __builtin_amdgcn_s_setprio(0);
    BAR();
  }

  // epilogue (direct stores)
#pragma unroll
  for (int i = 0; i < 8; i++) {
#pragma unroll
    for (int j = 0; j < 4; j++) {
#pragma unroll
      for (int r = 0; r < 4; r++) {
        int grow = m0 + wm * 128 + i * 16 + quad * 4 + r;
        int gcol = n0 + wn * 64 + j * 16 + lr;
        float v = acc[i][j][r];
        if (MODE == EP_F32) {
          float* C = (float*)Cout + (long long)z * cBatch;
          C[(long long)grow * ldc + gcol] = v;
        } else {  // EP_QK, interleaved pair layout: row pos 2u,2u+1
          int sel = gcol >> 10;        // uniform per block (n0 multiple of 256)
          int ucol = gcol & 1023;
          half_t h = (half_t)v;
          unsigned hu = h2u(h);
          unsigned val;
          half_t* base;
          if (sel == 0) {  // Q: [qh, ql] pairs
            val = hu | ((unsigned)h2u((half_t)(v - (float)h)) << 16);
            base = (half_t*)Cout;
          } else {         // K: [kh, kh] pairs
            val = hu | (hu << 16);
            base = CoutK;
          }
          *(unsigned*)(base + (long long)grow * KCAT + 2 * ucol) = val;
        }
      }
    }
  }
#undef SA
#undef SB
#undef LDA4
#undef LDB4
#undef MFMA16
}

// ---------- softmax, in place: S row (fp32[2048]) -> P row (fp16[2048]) ----------
__global__ __launch_bounds__(256) void k_softmax(float* __restrict__ Sbuf) {
  long long row = blockIdx.x;  // 0..8191
  float* p = Sbuf + row * 2048;
  int t = threadIdx.x;
  float4 v0 = ((const float4*)p)[t];
  float4 v1 = ((const float4*)p)[t + 256];
  float m = fmaxf(fmaxf(fmaxf(v0.x, v0.y), fmaxf(v0.z, v0.w)),
                  fmaxf(fmaxf(v1.x, v1.y), fmaxf(v1.z, v1.w)));
  for (int off = 32; off; off >>= 1) m = fmaxf(m, __shfl_xor(m, off));
  __shared__ float red[8];
  int wv = t >> 6, ln = t & 63;
  if (ln == 0) red[wv] = m;
  __syncthreads();
  m = fmaxf(fmaxf(red[0], red[1]), fmaxf(red[2], red[3]));
  float e0 = __expf(v0.x - m), e1 = __expf(v0.y - m), e2 = __expf(v0.z - m), e3 = __expf(v0.w - m);
  float e4 = __expf(v1.x - m), e5 = __expf(v1.y - m), e6 = __expf(v1.z - m), e7 = __expf(v1.w - m);
  float s = ((e0 + e1) + (e2 + e3)) + ((e4 + e5) + (e6 + e7));
  for (int off = 32; off; off >>= 1) s += __shfl_xor(s, off);
  if (ln == 0) red[4 + wv] = s;
  __syncthreads();
  s = (red[4] + red[5]) + (red[6] + red[7]);
  float inv = 1.0f / s;
  uint2 w0, w1;
  w0.x = (unsigned)h2u((half_t)(e0 * inv)) | ((unsigned)h2u((half_t)(e1 * inv)) << 16);
  w0.y = (unsigned)h2u((half_t)(e2 * inv)) | ((unsigned)h2u((half_t)(e3 * inv)) << 16);
  w1.x = (unsigned)h2u((half_t)(e4 * inv)) | ((unsigned)h2u((half_t)(e5 * inv)) << 16);
  w1.y = (unsigned)h2u((half_t)(e6 * inv)) | ((unsigned)h2u((half_t)(e7 * inv)) << 16);
  ((uint2*)p)[t] = w0;
  ((uint2*)p)[t + 256] = w1;
}

// ---------- host launch ----------
extern "C" void kernel_launch(void* const* d_in, const int* in_sizes, int n_in,
                              void* d_out, int out_size, void* d_ws, size_t ws_size,
                              hipStream_t stream) {
  (void)in_sizes; (void)n_in; (void)out_size;
  if (ws_size < WS_NEED) return;  // output stays poisoned -> visible failure

  const float* X = (const float*)d_in[0];
  const float* Wq = (const float*)d_in[1];
  const float* Wk = (const float*)d_in[2];
  const float* Wv = (const float*)d_in[3];
  char* ws = (char*)d_ws;
  half_t* xcat = (half_t*)(ws + XCAT_OFF);
  half_t* wt = (half_t*)(ws + WT_OFF);
  float* Sbuf = (float*)(ws + S_OFF);
  half_t* qcat = (half_t*)(ws + QCAT_OFF);
  half_t* kcat = (half_t*)(ws + KCAT_OFF);
  half_t* vt = (half_t*)(ws + VT_OFF);
  float* out = (float*)d_out;

  // 1. split X and W (fp16)
  k_split_x<<<dim3(MX * 1024 / 256), dim3(256), 0, stream>>>(X, xcat);
  k_split_wt<<<dim3(16, 16, 3), dim3(256), 0, stream>>>(Wq, Wk, Wv, wt);

  // 2a. fused QK projection: M=8192, N=2048 (Wq|Wk), K=2048 (2-term)
  k_gemm256<EP_QK><<<dim3(8, 32, 1), dim3(512), 0, stream>>>(
      xcat, 0LL, KCAT, wt, 0LL, KCAT, qcat, 0LL, 0, KCAT, kcat);

  // 2b. V projection: M=8192, N=1024, K=1024 (1-term) -- 128^2, 4 blocks/CU
  k_gemm<EP_VT><<<dim3(8, 64, 1), dim3(256), 0, stream>>>(
      xcat, 0LL, KCAT, wt + 2 * 1024 * KCAT, 0LL, KCAT, vt, 0LL, 0, 1024, nullptr);

  // 3. scores S = Q K^T (fp16 2-term, interleaved k-layout on both sides)
  k_gemm256<EP_F32><<<dim3(8, 8, 4), dim3(512), 0, stream>>>(
      qcat, (long long)2048 * KCAT, KCAT, kcat, (long long)2048 * KCAT, KCAT,
      Sbuf, (long long)2048 * 2048, 2048, KCAT, nullptr);

  // 4. softmax in place (fp32 row -> fp16 row; row stride becomes 4096 halves)
  k_softmax<<<dim3(8192), dim3(256), 0, stream>>>(Sbuf);

  // 5. O = P V (plain fp16), fp32 out: per batch M=2048, N=1024, K=2048
  k_gemm<EP_F32><<<dim3(8, 16, 4), dim3(256), 0, stream>>>(
      (const half_t*)Sbuf, (long long)2048 * 4096, 4096,
      vt, (long long)1024 * 2048, 2048,
      out, (long long)2048 * 1024, 1024, 2048, nullptr);
}

// Round 6
// 317.548 us; speedup vs baseline: 1.3578x; 1.0024x over previous
//
#include <hip/hip_runtime.h>
#include <cstdint>
#include <cstddef>

// B=4, S=2048, D=1024, U=1024 self-attention, fp32 in/out.
// R13 = R12 (XCD swizzle FETCH 135->49MB verified; packed EP_QK) + depth-1
//       register prefetch in the k_gemm256 K-loop: phase k+1's ds_reads are
//       issued before phase k's MFMA cluster, lgkmcnt(0) drain removed ->
//       compiler emits exact counted waits. Attacks the serial LDS<->MFMA
//       alternation that caps MfmaUtil at ~36% (cycle model: 768cy LDS read
//       + 256cy DMA write vs 614cy MFMA per K-tile, fully serialized).
// Ledger (verified): G1=P1 frags issued in P0; G2=P2 frags in P1; G3=P3
// frags in P2; next tile's G0 in P3 AFTER vmcnt(6)+mid-barrier (all waves'
// t+1 staging confirmed). Every prefetched read drains (compiler wait before
// its MFMA) >=1 barrier before the staging that overwrites its region.

typedef unsigned short ushort_t;
typedef _Float16 half_t;
typedef __attribute__((ext_vector_type(8))) short short8;
typedef __attribute__((ext_vector_type(4))) float floatx4;

__device__ inline unsigned short h2u(half_t h) {
  union { half_t h; unsigned short u; } v; v.h = h; return v.u;
}

// async 16B global -> LDS (DMA). LDS dest = wave-uniform base + lane*16 (HW).
__device__ __forceinline__ void gload16(const half_t* g, half_t* l) {
  __builtin_amdgcn_global_load_lds(
      (const __attribute__((address_space(1))) unsigned int*)g,
      (__attribute__((address_space(3))) unsigned int*)l, 16, 0, 0);
}

#define BAR() asm volatile("s_barrier" ::: "memory")
#define LGKM0() asm volatile("s_waitcnt lgkmcnt(0)" ::: "memory")
#define VM6() asm volatile("s_waitcnt vmcnt(6)" ::: "memory")
#define VM0() asm volatile("s_waitcnt vmcnt(0)" ::: "memory")

// ---------- constants ----------
#define MX 8192       // B*S
#define KCAT 2048     // 2*D (fp16 2-term split-concatenated K dim)

// ws byte offsets (regions reused across phases; S overwrites xcat/wt)
#define XCAT_OFF 0UL                  // half [8192][2048] = 33554432 B
#define WT_OFF   50331648UL           // half 3 x [1024][2048] = 12582912 B
#define S_OFF    0UL                  // float [4][2048][2048] = 67108864 B
#define QCAT_OFF 69206016UL           // half [8192][2048]
#define KCAT_OFF 119537664UL          // half [8192][2048]
#define VT_OFF   169869312UL          // half [4][1024][2048] = 16777216 B
#define WS_NEED  186646528UL

// XCD-aware bijective rectangle remap (verified: FETCH 135->49MB).
// Assumes XCD = linear_bid % 8. Requires gridDim.x == 8 and
// gridDim.y*gridDim.z % 4 == 0 (true for all four GEMM launches).
#define XCD_REMAP(BX, BY, BZ)                                              \
  const int fbid_ = blockIdx.x + 8 * (blockIdx.y + gridDim.y * blockIdx.z); \
  const int xj_ = fbid_ & 7, xi_ = fbid_ >> 3;                              \
  const int BX = ((xj_ & 1) << 2) | (xi_ & 3);                              \
  const int nrow_ = (xj_ >> 1) * ((gridDim.y * gridDim.z) >> 2) + (xi_ >> 2);\
  const int BY = nrow_ % gridDim.y;                                         \
  const int BZ = nrow_ / gridDim.y;

// ---------- K1a: split inputs X -> Xcat = [xh | xl] (fp16) ----------
__global__ __launch_bounds__(256) void k_split_x(const float* __restrict__ X,
                                                 half_t* __restrict__ xcat) {
  long long i = (long long)blockIdx.x * 256 + threadIdx.x;  // over 8192*1024
  float x = X[i];
  half_t h = (half_t)x;
  half_t lo = (half_t)(x - (float)h);
  long long row = i >> 10;
  int col = (int)(i & 1023);
  half_t* r = xcat + row * KCAT;
  r[col] = h;
  r[col + 1024] = lo;
}

// ---------- K1b: transpose W -> WT_cat = [Wh | Wh] per weight ----------
__global__ __launch_bounds__(256) void k_split_wt(const float* __restrict__ Wq,
                                                  const float* __restrict__ Wk,
                                                  const float* __restrict__ Wv,
                                                  half_t* __restrict__ wt) {
  __shared__ float tile[64][65];
  const float* W = (blockIdx.z == 0) ? Wq : ((blockIdx.z == 1) ? Wk : Wv);
  half_t* out = wt + (size_t)blockIdx.z * 1024 * KCAT;
  int d0 = blockIdx.y * 64, u0 = blockIdx.x * 64;
  int t = threadIdx.x;
  int tr = t >> 6, tc = t & 63;
  for (int r = 0; r < 64; r += 4)
    tile[r + tr][tc] = W[(size_t)(d0 + r + tr) * 1024 + (u0 + tc)];
  __syncthreads();
  for (int r = 0; r < 64; r += 4) {
    int urow = r + tr, dcol = tc;
    float x = tile[dcol][urow];  // = WT[u0+urow][d0+dcol]
    half_t h = (half_t)x;
    half_t* o = out + (size_t)(u0 + urow) * KCAT + d0;
    o[dcol] = h;
    o[dcol + 1024] = h;
  }
}

enum { EP_F32 = 0, EP_QK = 1, EP_VT = 2 };

// ---------- old 128x128 GEMM (V-proj EP_VT; PV EP_F32) ----------
template <int MODE>
__global__ __launch_bounds__(256, 4) void k_gemm(
    const half_t* __restrict__ A, long long aBatch, int lda,
    const half_t* __restrict__ Bt, long long bBatch, int ldb,
    void* __restrict__ Cout, long long cBatch, int ldc, int K,
    half_t* __restrict__ CoutK) {
  __shared__ __align__(16) half_t As[128 * 64];
  __shared__ __align__(16) half_t Bs[128 * 64];
  const int t = threadIdx.x;
  XCD_REMAP(bx, by, z);
  A += (long long)z * aBatch;
  Bt += (long long)z * bBatch;
  const int m0 = by * 128, n0 = bx * 128;

  const int w = t >> 6, l = t & 63;
  const int lr = l & 15, quad = l >> 4;
  const int wm = (w >> 1) * 64, wn = (w & 1) * 64;

  const floatx4 fz = {0.f, 0.f, 0.f, 0.f};
  floatx4 acc[4][4];
#pragma unroll
  for (int i = 0; i < 4; i++)
#pragma unroll
    for (int j = 0; j < 4; j++) acc[i][j] = fz;

  const half_t* Ap[4];
  const half_t* Bp[4];
  half_t* ldsA[4];
  half_t* ldsB[4];
#pragma unroll
  for (int s = 0; s < 4; s++) {
    int c = s * 256 + t;
    int row = c >> 3, gq = (c & 7) ^ ((c >> 3) & 7);
    Ap[s] = A + (long long)(m0 + row) * lda + gq * 8;
    Bp[s] = Bt + (long long)(n0 + row) * ldb + gq * 8;
    ldsA[s] = &As[(s * 256 + w * 64) * 8];
    ldsB[s] = &Bs[(s * 256 + w * 64) * 8];
  }

  const int p0 = quad ^ (lr & 7);
  const int p1 = (quad + 4) ^ (lr & 7);
  const int arow = (wm + lr) * 64, brow = (wn + lr) * 64;

  for (int kb = 0; kb < K; kb += 64) {
    __syncthreads();
#pragma unroll
    for (int s = 0; s < 4; s++) {
      gload16(Ap[s] + kb, ldsA[s]);
      gload16(Bp[s] + kb, ldsB[s]);
    }
    __syncthreads();
#pragma unroll
    for (int s = 0; s < 2; s++) {
      const int pp = s ? p1 : p0;
      short8 af[4], bfg[4];
#pragma unroll
      for (int j = 0; j < 4; j++) bfg[j] = *(const short8*)&Bs[brow + j * 1024 + pp * 8];
#pragma unroll
      for (int i = 0; i < 4; i++) af[i] = *(const short8*)&As[arow + i * 1024 + pp * 8];
#pragma unroll
      for (int i = 0; i < 4; i++)
#pragma unroll
        for (int j = 0; j < 4; j++)
          acc[i][j] = __builtin_amdgcn_mfma_f32_16x16x32_f16(af[i], bfg[j], acc[i][j], 0, 0, 0);
    }
  }

#pragma unroll
  for (int i = 0; i < 4; i++) {
#pragma unroll
    for (int j = 0; j < 4; j++) {
#pragma unroll
      for (int r = 0; r < 4; r++) {
        int grow = m0 + wm + i * 16 + quad * 4 + r;
        int gcol = n0 + wn + j * 16 + lr;
        float v = acc[i][j][r];
        if (MODE == EP_F32) {
          float* C = (float*)Cout + (long long)z * cBatch;
          C[(long long)grow * ldc + gcol] = v;
        } else {  // EP_VT: V^T[b][u][s] = V[b*2048+s][u]
          half_t* C = (half_t*)Cout;
          int b = grow >> 11, s = grow & 2047;
          C[((long long)b * 1024 + gcol) * 2048 + s] = (half_t)v;
        }
      }
    }
  }
}

// ---------- 256x256 GEMM, 4-phase core + depth-1 register prefetch ----------
// 8 waves (2M x 4N), per-wave 128x64 output = acc[8][4] frags of 16x16x32.
// LDS per matrix: [dbuf:2][khalf:2][256 rows][32 halves] = 64 KiB; total 128.
// Stage issues unchanged (ledger): P0 -> (t+1).A-kh1, P1 -> (t+2).B-kh0,
// P2 -> (t+2).A-kh0, P3 -> (t+2).B-kh1 then vmcnt(6).
// NEW: fragment ds_reads prefetched one phase ahead (two reg sets aA/aB,
// bA/bB); no lgkmcnt(0) -- compiler emits exact counted waits before MFMAs.
template <int MODE>
__global__ __launch_bounds__(512, 2) void k_gemm256(
    const half_t* __restrict__ A, long long aBatch, int lda,
    const half_t* __restrict__ Bt, long long bBatch, int ldb,
    void* __restrict__ Cout, long long cBatch, int ldc, int K,
    half_t* __restrict__ CoutK) {
  __shared__ __align__(16) half_t As[32768];  // [2][2][256*32]
  __shared__ __align__(16) half_t Bs[32768];
  const int tid = threadIdx.x;
  XCD_REMAP(bx, by, z);
  A += (long long)z * aBatch;
  Bt += (long long)z * bBatch;
  const int m0 = by * 256, n0 = bx * 256;
  const int w = tid >> 6, l = tid & 63;
  const int lr = l & 15, quad = l >> 4;
  const int wm = w >> 2, wn = w & 3;

  const floatx4 fz = {0.f, 0.f, 0.f, 0.f};
  floatx4 acc[8][4];
#pragma unroll
  for (int i = 0; i < 8; i++)
#pragma unroll
    for (int j = 0; j < 4; j++) acc[i][j] = fz;

  // staging: chunk c in [0,1024) per k-half: row=c>>2, phys=c&3,
  // global chunk gq = (c&3)^((c>>3)&3). Thread stages c = tid and 512+tid.
  const int r0 = tid >> 2;
  const int gq0 = (tid & 3) ^ ((tid >> 3) & 3);
  const half_t* aS0 = A + (long long)(m0 + r0) * lda + gq0 * 8;
  const half_t* aS1 = aS0 + (long long)128 * lda;
  const half_t* bS0 = Bt + (long long)(n0 + r0) * ldb + gq0 * 8;
  const half_t* bS1 = bS0 + (long long)128 * ldb;
  const int wso = w << 9;  // wave-uniform LDS chunk base

  // frag read: row = Rbase + lr, phys chunk = quad ^ ((lr>>1)&3)
  const int swz = (quad ^ ((lr >> 1) & 3)) << 3;
  const int aBase = wm * 4096 + lr * 32 + swz;
  const int bBase = wn * 2048 + lr * 32 + swz;
  const int NT = K >> 6;

#define SA(BUF, KH, KOFF) do { half_t* d_ = &As[(BUF) * 16384 + (KH) * 8192 + wso]; \
    gload16(aS0 + (KOFF), d_); gload16(aS1 + (KOFF), d_ + 4096); } while (0)
#define SB(BUF, KH, KOFF) do { half_t* d_ = &Bs[(BUF) * 16384 + (KH) * 8192 + wso]; \
    gload16(bS0 + (KOFF), d_); gload16(bS1 + (KOFF), d_ + 4096); } while (0)
#define LDA4(S, OFF) { const half_t* ap_ = &As[(OFF)]; \
    S##0 = *(const short8*)(ap_); S##1 = *(const short8*)(ap_ + 512); \
    S##2 = *(const short8*)(ap_ + 1024); S##3 = *(const short8*)(ap_ + 1536); }
#define LDB4(S, OFF) { const half_t* bp_ = &Bs[(OFF)]; \
    S##0 = *(const short8*)(bp_); S##1 = *(const short8*)(bp_ + 512); \
    S##2 = *(const short8*)(bp_ + 1024); S##3 = *(const short8*)(bp_ + 1536); }
#define MFMA16(I0, AS, BS) do { \
    acc[(I0) + 0][0] = __builtin_amdgcn_mfma_f32_16x16x32_f16(AS##0, BS##0, acc[(I0) + 0][0], 0, 0, 0); \
    acc[(I0) + 0][1] = __builtin_amdgcn_mfma_f32_16x16x32_f16(AS##0, BS##1, acc[(I0) + 0][1], 0, 0, 0); \
    acc[(I0) + 0][2] = __builtin_amdgcn_mfma_f32_16x16x32_f16(AS##0, BS##2, acc[(I0) + 0][2], 0, 0, 0); \
    acc[(I0) + 0][3] = __builtin_amdgcn_mfma_f32_16x16x32_f16(AS##0, BS##3, acc[(I0) + 0][3], 0, 0, 0); \
    acc[(I0) + 1][0] = __builtin_amdgcn_mfma_f32_16x16x32_f16(AS##1, BS##0, acc[(I0) + 1][0], 0, 0, 0); \
    acc[(I0) + 1][1] = __builtin_amdgcn_mfma_f32_16x16x32_f16(AS##1, BS##1, acc[(I0) + 1][1], 0, 0, 0); \
    acc[(I0) + 1][2] = __builtin_amdgcn_mfma_f32_16x16x32_f16(AS##1, BS##2, acc[(I0) + 1][2], 0, 0, 0); \
    acc[(I0) + 1][3] = __builtin_amdgcn_mfma_f32_16x16x32_f16(AS##1, BS##3, acc[(I0) + 1][3], 0, 0, 0); \
    acc[(I0) + 2][0] = __builtin_amdgcn_mfma_f32_16x16x32_f16(AS##2, BS##0, acc[(I0) + 2][0], 0, 0, 0); \
    acc[(I0) + 2][1] = __builtin_amdgcn_mfma_f32_16x16x32_f16(AS##2, BS##1, acc[(I0) + 2][1], 0, 0, 0); \
    acc[(I0) + 2][2] = __builtin_amdgcn_mfma_f32_16x16x32_f16(AS##2, BS##2, acc[(I0) + 2][2], 0, 0, 0); \
    acc[(I0) + 2][3] = __builtin_amdgcn_mfma_f32_16x16x32_f16(AS##2, BS##3, acc[(I0) + 2][3], 0, 0, 0); \
    acc[(I0) + 3][0] = __builtin_amdgcn_mfma_f32_16x16x32_f16(AS##3, BS##0, acc[(I0) + 3][0], 0, 0, 0); \
    acc[(I0) + 3][1] = __builtin_amdgcn_mfma_f32_16x16x32_f16(AS##3, BS##1, acc[(I0) + 3][1], 0, 0, 0); \
    acc[(I0) + 3][2] = __builtin_amdgcn_mfma_f32_16x16x32_f16(AS##3, BS##2, acc[(I0) + 3][2], 0, 0, 0); \
    acc[(I0) + 3][3] = __builtin_amdgcn_mfma_f32_16x16x32_f16(AS##3, BS##3, acc[(I0) + 3][3], 0, 0, 0); \
  } while (0)

  short8 aA0, aA1, aA2, aA3;  // A frags, set A (kh0 M0-3 / kh1 M0-3)
  short8 aB0, aB1, aB2, aB3;  // A frags, set B (kh0 M4-7 / kh1 M4-7)
  short8 bA0, bA1, bA2, bA3;  // B frags kh0
  short8 bB0, bB1, bB2, bB3;  // B frags kh1

  // prologue: tile0 fully + tile1 {B-kh0, A-kh0, B-kh1}; last 3 stay in flight
  SB(0, 0, 0); SA(0, 0, 0); SB(0, 1, 32); SA(0, 1, 32);
  SB(1, 0, 64); SA(1, 0, 64); SB(1, 1, 96);
  VM6();
  BAR();
  // G0 for tile 0 (tile0 LDS confirmed by VM6+BAR)
  LDA4(aA, aBase);
  LDB4(bA, bBase);

  for (int t = 0; t < NT; ++t) {
    const int buf = t & 1, nbuf = buf ^ 1;
    const int ab = buf * 16384, nab = nbuf * 16384;
    const int kb = t * 64;

    // ---- P0: MFMA kh0 M0-3 (aA,bA in regs); prefetch G1 = kh0 M4-7 ----
    LDA4(aB, ab + aBase + 2048);
    if (t + 1 < NT) SA(nbuf, 1, kb + 96);  // (t+1).A-kh1
    BAR();
    __builtin_amdgcn_s_setprio(1); MFMA16(0, aA, bA); __builtin_amdgcn_s_setprio(0);
    BAR();

    // ---- P1: MFMA kh0 M4-7 (aB,bA); prefetch G2 = kh1 M0-3 + B-kh1 ----
    LDA4(aA, ab + 8192 + aBase);
    LDB4(bB, ab + 8192 + bBase);
    if (t + 2 < NT) SB(buf, 0, kb + 128);  // (t+2).B-kh0
    BAR();
    __builtin_amdgcn_s_setprio(1); MFMA16(4, aB, bA); __builtin_amdgcn_s_setprio(0);
    BAR();

    // ---- P2: MFMA kh1 M0-3 (aA,bB); prefetch G3 = kh1 M4-7 ----
    LDA4(aB, ab + 8192 + aBase + 2048);
    if (t + 2 < NT) SA(buf, 0, kb + 128);  // (t+2).A-kh0
    BAR();
    __builtin_amdgcn_s_setprio(1); MFMA16(0, aA, bB); __builtin_amdgcn_s_setprio(0);
    BAR();

    // ---- P3: MFMA kh1 M4-7 (aB,bB); after VM6+mid-BAR prefetch next G0 ----
    if (t + 2 < NT) SB(buf, 1, kb + 160);  // (t+2).B-kh1
    if (t < NT - 2) { VM6(); } else if (t == NT - 2) { VM0(); }  // tail drains
    BAR();  // all waves passed vmcnt -> tile t+1 LDS fully landed
    __builtin_amdgcn_s_setprio(1); MFMA16(4, aB, bB); __builtin_amdgcn_s_setprio(0);
    if (t + 1 < NT) {  // next tile's G0 (reads nbuf kh0; overwritten only t+1.P1/P2)
      LDA4(aA, nab + aBase);
      LDB4(bA, nab + bBase);
    }
    BAR();
  }

  // epilogue (direct stores)
#pragma unroll
  for (int i = 0; i < 8; i++) {
#pragma unroll
    for (int j = 0; j < 4; j++) {
#pragma unroll
      for (int r = 0; r < 4; r++) {
        int grow = m0 + wm * 128 + i * 16 + quad * 4 + r;
        int gcol = n0 + wn * 64 + j * 16 + lr;
        float v = acc[i][j][r];
        if (MODE == EP_F32) {
          float* C = (float*)Cout + (long long)z * cBatch;
          C[(long long)grow * ldc + gcol] = v;
        } else {  // EP_QK, interleaved pair layout: row pos 2u,2u+1
          int sel = gcol >> 10;        // uniform per block (n0 multiple of 256)
          int ucol = gcol & 1023;
          half_t h = (half_t)v;
          unsigned hu = h2u(h);
          unsigned val;
          half_t* base;
          if (sel == 0) {  // Q: [qh, ql] pairs
            val = hu | ((unsigned)h2u((half_t)(v - (float)h)) << 16);
            base = (half_t*)Cout;
          } else {         // K: [kh, kh] pairs
            val = hu | (hu << 16);
            base = CoutK;
          }
          *(unsigned*)(base + (long long)grow * KCAT + 2 * ucol) = val;
        }
      }
    }
  }
#undef SA
#undef SB
#undef LDA4
#undef LDB4
#undef MFMA16
}

// ---------- softmax, in place: S row (fp32[2048]) -> P row (fp16[2048]) ----------
__global__ __launch_bounds__(256) void k_softmax(float* __restrict__ Sbuf) {
  long long row = blockIdx.x;  // 0..8191
  float* p = Sbuf + row * 2048;
  int t = threadIdx.x;
  float4 v0 = ((const float4*)p)[t];
  float4 v1 = ((const float4*)p)[t + 256];
  float m = fmaxf(fmaxf(fmaxf(v0.x, v0.y), fmaxf(v0.z, v0.w)),
                  fmaxf(fmaxf(v1.x, v1.y), fmaxf(v1.z, v1.w)));
  for (int off = 32; off; off >>= 1) m = fmaxf(m, __shfl_xor(m, off));
  __shared__ float red[8];
  int wv = t >> 6, ln = t & 63;
  if (ln == 0) red[wv] = m;
  __syncthreads();
  m = fmaxf(fmaxf(red[0], red[1]), fmaxf(red[2], red[3]));
  float e0 = __expf(v0.x - m), e1 = __expf(v0.y - m), e2 = __expf(v0.z - m), e3 = __expf(v0.w - m);
  float e4 = __expf(v1.x - m), e5 = __expf(v1.y - m), e6 = __expf(v1.z - m), e7 = __expf(v1.w - m);
  float s = ((e0 + e1) + (e2 + e3)) + ((e4 + e5) + (e6 + e7));
  for (int off = 32; off; off >>= 1) s += __shfl_xor(s, off);
  if (ln == 0) red[4 + wv] = s;
  __syncthreads();
  s = (red[4] + red[5]) + (red[6] + red[7]);
  float inv = 1.0f / s;
  uint2 w0, w1;
  w0.x = (unsigned)h2u((half_t)(e0 * inv)) | ((unsigned)h2u((half_t)(e1 * inv)) << 16);
  w0.y = (unsigned)h2u((half_t)(e2 * inv)) | ((unsigned)h2u((half_t)(e3 * inv)) << 16);
  w1.x = (unsigned)h2u((half_t)(e4 * inv)) | ((unsigned)h2u((half_t)(e5 * inv)) << 16);
  w1.y = (unsigned)h2u((half_t)(e6 * inv)) | ((unsigned)h2u((half_t)(e7 * inv)) << 16);
  ((uint2*)p)[t] = w0;
  ((uint2*)p)[t + 256] = w1;
}

// ---------- host launch ----------
extern "C" void kernel_launch(void* const* d_in, const int* in_sizes, int n_in,
                              void* d_out, int out_size, void* d_ws, size_t ws_size,
                              hipStream_t stream) {
  (void)in_sizes; (void)n_in; (void)out_size;
  if (ws_size < WS_NEED) return;  // output stays poisoned -> visible failure

  const float* X = (const float*)d_in[0];
  const float* Wq = (const float*)d_in[1];
  const float* Wk = (const float*)d_in[2];
  const float* Wv = (const float*)d_in[3];
  char* ws = (char*)d_ws;
  half_t* xcat = (half_t*)(ws + XCAT_OFF);
  half_t* wt = (half_t*)(ws + WT_OFF);
  float* Sbuf = (float*)(ws + S_OFF);
  half_t* qcat = (half_t*)(ws + QCAT_OFF);
  half_t* kcat = (half_t*)(ws + KCAT_OFF);
  half_t* vt = (half_t*)(ws + VT_OFF);
  float* out = (float*)d_out;

  // 1. split X and W (fp16)
  k_split_x<<<dim3(MX * 1024 / 256), dim3(256), 0, stream>>>(X, xcat);
  k_split_wt<<<dim3(16, 16, 3), dim3(256), 0, stream>>>(Wq, Wk, Wv, wt);

  // 2a. fused QK projection: M=8192, N=2048 (Wq|Wk), K=2048 (2-term)
  k_gemm256<EP_QK><<<dim3(8, 32, 1), dim3(512), 0, stream>>>(
      xcat, 0LL, KCAT, wt, 0LL, KCAT, qcat, 0LL, 0, KCAT, kcat);

  // 2b. V projection: M=8192, N=1024, K=1024 (1-term) -- 128^2, 4 blocks/CU
  k_gemm<EP_VT><<<dim3(8, 64, 1), dim3(256), 0, stream>>>(
      xcat, 0LL, KCAT, wt + 2 * 1024 * KCAT, 0LL, KCAT, vt, 0LL, 0, 1024, nullptr);

  // 3. scores S = Q K^T (fp16 2-term, interleaved k-layout on both sides)
  k_gemm256<EP_F32><<<dim3(8, 8, 4), dim3(512), 0, stream>>>(
      qcat, (long long)2048 * KCAT, KCAT, kcat, (long long)2048 * KCAT, KCAT,
      Sbuf, (long long)2048 * 2048, 2048, KCAT, nullptr);

  // 4. softmax in place (fp32 row -> fp16 row; row stride becomes 4096 halves)
  k_softmax<<<dim3(8192), dim3(256), 0, stream>>>(Sbuf);

  // 5. O = P V (plain fp16), fp32 out: per batch M=2048, N=1024, K=2048
  k_gemm<EP_F32><<<dim3(8, 16, 4), dim3(256), 0, stream>>>(
      (const half_t*)Sbuf, (long long)2048 * 4096, 4096,
      vt, (long long)1024 * 2048, 2048,
      out, (long long)2048 * 1024, 1024, 2048, nullptr);
}

// Round 7
// 314.974 us; speedup vs baseline: 1.3689x; 1.0082x over previous
//
#include <hip/hip_runtime.h>
#include <cstdint>
#include <cstddef>

// B=4, S=2048, D=1024, U=1024 self-attention, fp32 in/out.
// R14 = R13 (XCD swizzle, packed EP_QK) with k_gemm256 K-loop merged from
//       4 phases -> 2 phases per K-tile (32 MFMA per phase). Diagnosis: both
//       pipes half-idle; wall = 6000cy/tile vs m201's 3290 at same geometry;
//       ~880cy fixed overhead per phase x 8 barriers dominates. Halving the
//       phase count doubles MFMA per barrier interval (1240cy/SIMD cluster).
// Ledger (re-derived): (u).A stages (u+1).kh1 [last read (u-1).B, drained by
// LGKM0 before its MFMA]; (u).B stages (u+2).kh0 [last read (u).A]. vmcnt(8)
// steady (confirms loads issued 2 phases back); tail A:VM0@NT-1, B:VM4@NT-2.

typedef unsigned short ushort_t;
typedef _Float16 half_t;
typedef __attribute__((ext_vector_type(8))) short short8;
typedef __attribute__((ext_vector_type(4))) float floatx4;

__device__ inline unsigned short h2u(half_t h) {
  union { half_t h; unsigned short u; } v; v.h = h; return v.u;
}

// async 16B global -> LDS (DMA). LDS dest = wave-uniform base + lane*16 (HW).
__device__ __forceinline__ void gload16(const half_t* g, half_t* l) {
  __builtin_amdgcn_global_load_lds(
      (const __attribute__((address_space(1))) unsigned int*)g,
      (__attribute__((address_space(3))) unsigned int*)l, 16, 0, 0);
}

#define BAR() asm volatile("s_barrier" ::: "memory")
#define LGKM0() asm volatile("s_waitcnt lgkmcnt(0)" ::: "memory")
#define VM8() asm volatile("s_waitcnt vmcnt(8)" ::: "memory")
#define VM4() asm volatile("s_waitcnt vmcnt(4)" ::: "memory")
#define VM0() asm volatile("s_waitcnt vmcnt(0)" ::: "memory")

// ---------- constants ----------
#define MX 8192       // B*S
#define KCAT 2048     // 2*D (fp16 2-term split-concatenated K dim)

// ws byte offsets (regions reused across phases; S overwrites xcat/wt)
#define XCAT_OFF 0UL                  // half [8192][2048] = 33554432 B
#define WT_OFF   50331648UL           // half 3 x [1024][2048] = 12582912 B
#define S_OFF    0UL                  // float [4][2048][2048] = 67108864 B
#define QCAT_OFF 69206016UL           // half [8192][2048]
#define KCAT_OFF 119537664UL          // half [8192][2048]
#define VT_OFF   169869312UL          // half [4][1024][2048] = 16777216 B
#define WS_NEED  186646528UL

// XCD-aware bijective rectangle remap (verified: FETCH 135->49MB).
// Assumes XCD = linear_bid % 8. Requires gridDim.x == 8 and
// gridDim.y*gridDim.z % 4 == 0 (true for all four GEMM launches).
#define XCD_REMAP(BX, BY, BZ)                                              \
  const int fbid_ = blockIdx.x + 8 * (blockIdx.y + gridDim.y * blockIdx.z); \
  const int xj_ = fbid_ & 7, xi_ = fbid_ >> 3;                              \
  const int BX = ((xj_ & 1) << 2) | (xi_ & 3);                              \
  const int nrow_ = (xj_ >> 1) * ((gridDim.y * gridDim.z) >> 2) + (xi_ >> 2);\
  const int BY = nrow_ % gridDim.y;                                         \
  const int BZ = nrow_ / gridDim.y;

// ---------- K1a: split inputs X -> Xcat = [xh | xl] (fp16) ----------
__global__ __launch_bounds__(256) void k_split_x(const float* __restrict__ X,
                                                 half_t* __restrict__ xcat) {
  long long i = (long long)blockIdx.x * 256 + threadIdx.x;  // over 8192*1024
  float x = X[i];
  half_t h = (half_t)x;
  half_t lo = (half_t)(x - (float)h);
  long long row = i >> 10;
  int col = (int)(i & 1023);
  half_t* r = xcat + row * KCAT;
  r[col] = h;
  r[col + 1024] = lo;
}

// ---------- K1b: transpose W -> WT_cat = [Wh | Wh] per weight ----------
__global__ __launch_bounds__(256) void k_split_wt(const float* __restrict__ Wq,
                                                  const float* __restrict__ Wk,
                                                  const float* __restrict__ Wv,
                                                  half_t* __restrict__ wt) {
  __shared__ float tile[64][65];
  const float* W = (blockIdx.z == 0) ? Wq : ((blockIdx.z == 1) ? Wk : Wv);
  half_t* out = wt + (size_t)blockIdx.z * 1024 * KCAT;
  int d0 = blockIdx.y * 64, u0 = blockIdx.x * 64;
  int t = threadIdx.x;
  int tr = t >> 6, tc = t & 63;
  for (int r = 0; r < 64; r += 4)
    tile[r + tr][tc] = W[(size_t)(d0 + r + tr) * 1024 + (u0 + tc)];
  __syncthreads();
  for (int r = 0; r < 64; r += 4) {
    int urow = r + tr, dcol = tc;
    float x = tile[dcol][urow];  // = WT[u0+urow][d0+dcol]
    half_t h = (half_t)x;
    half_t* o = out + (size_t)(u0 + urow) * KCAT + d0;
    o[dcol] = h;
    o[dcol + 1024] = h;
  }
}

enum { EP_F32 = 0, EP_QK = 1, EP_VT = 2 };

// ---------- old 128x128 GEMM (V-proj EP_VT; PV EP_F32) ----------
template <int MODE>
__global__ __launch_bounds__(256, 4) void k_gemm(
    const half_t* __restrict__ A, long long aBatch, int lda,
    const half_t* __restrict__ Bt, long long bBatch, int ldb,
    void* __restrict__ Cout, long long cBatch, int ldc, int K,
    half_t* __restrict__ CoutK) {
  __shared__ __align__(16) half_t As[128 * 64];
  __shared__ __align__(16) half_t Bs[128 * 64];
  const int t = threadIdx.x;
  XCD_REMAP(bx, by, z);
  A += (long long)z * aBatch;
  Bt += (long long)z * bBatch;
  const int m0 = by * 128, n0 = bx * 128;

  const int w = t >> 6, l = t & 63;
  const int lr = l & 15, quad = l >> 4;
  const int wm = (w >> 1) * 64, wn = (w & 1) * 64;

  const floatx4 fz = {0.f, 0.f, 0.f, 0.f};
  floatx4 acc[4][4];
#pragma unroll
  for (int i = 0; i < 4; i++)
#pragma unroll
    for (int j = 0; j < 4; j++) acc[i][j] = fz;

  const half_t* Ap[4];
  const half_t* Bp[4];
  half_t* ldsA[4];
  half_t* ldsB[4];
#pragma unroll
  for (int s = 0; s < 4; s++) {
    int c = s * 256 + t;
    int row = c >> 3, gq = (c & 7) ^ ((c >> 3) & 7);
    Ap[s] = A + (long long)(m0 + row) * lda + gq * 8;
    Bp[s] = Bt + (long long)(n0 + row) * ldb + gq * 8;
    ldsA[s] = &As[(s * 256 + w * 64) * 8];
    ldsB[s] = &Bs[(s * 256 + w * 64) * 8];
  }

  const int p0 = quad ^ (lr & 7);
  const int p1 = (quad + 4) ^ (lr & 7);
  const int arow = (wm + lr) * 64, brow = (wn + lr) * 64;

  for (int kb = 0; kb < K; kb += 64) {
    __syncthreads();
#pragma unroll
    for (int s = 0; s < 4; s++) {
      gload16(Ap[s] + kb, ldsA[s]);
      gload16(Bp[s] + kb, ldsB[s]);
    }
    __syncthreads();
#pragma unroll
    for (int s = 0; s < 2; s++) {
      const int pp = s ? p1 : p0;
      short8 af[4], bfg[4];
#pragma unroll
      for (int j = 0; j < 4; j++) bfg[j] = *(const short8*)&Bs[brow + j * 1024 + pp * 8];
#pragma unroll
      for (int i = 0; i < 4; i++) af[i] = *(const short8*)&As[arow + i * 1024 + pp * 8];
#pragma unroll
      for (int i = 0; i < 4; i++)
#pragma unroll
        for (int j = 0; j < 4; j++)
          acc[i][j] = __builtin_amdgcn_mfma_f32_16x16x32_f16(af[i], bfg[j], acc[i][j], 0, 0, 0);
    }
  }

#pragma unroll
  for (int i = 0; i < 4; i++) {
#pragma unroll
    for (int j = 0; j < 4; j++) {
#pragma unroll
      for (int r = 0; r < 4; r++) {
        int grow = m0 + wm + i * 16 + quad * 4 + r;
        int gcol = n0 + wn + j * 16 + lr;
        float v = acc[i][j][r];
        if (MODE == EP_F32) {
          float* C = (float*)Cout + (long long)z * cBatch;
          C[(long long)grow * ldc + gcol] = v;
        } else {  // EP_VT: V^T[b][u][s] = V[b*2048+s][u]
          half_t* C = (half_t*)Cout;
          int b = grow >> 11, s = grow & 2047;
          C[((long long)b * 1024 + gcol) * 2048 + s] = (half_t)v;
        }
      }
    }
  }
}

// ---------- 256x256 GEMM, 2-phase-per-K-tile counted-vmcnt schedule ----------
// 8 waves (2M x 4N), per-wave 128x64 output = acc[8][4] frags of 16x16x32.
// LDS per matrix: [dbuf:2][khalf:2][256 rows][32 halves] = 64 KiB; total 128.
// Per phase: 12 ds_read_b128 + 2 stage-ops (4 gload16) + vmcnt + BAR +
// lgkmcnt(0) + 32 MFMA + BAR. 4 barriers per K-tile (was 8).
template <int MODE>
__global__ __launch_bounds__(512, 2) void k_gemm256(
    const half_t* __restrict__ A, long long aBatch, int lda,
    const half_t* __restrict__ Bt, long long bBatch, int ldb,
    void* __restrict__ Cout, long long cBatch, int ldc, int K,
    half_t* __restrict__ CoutK) {
  __shared__ __align__(16) half_t As[32768];  // [2][2][256*32]
  __shared__ __align__(16) half_t Bs[32768];
  const int tid = threadIdx.x;
  XCD_REMAP(bx, by, z);
  A += (long long)z * aBatch;
  Bt += (long long)z * bBatch;
  const int m0 = by * 256, n0 = bx * 256;
  const int w = tid >> 6, l = tid & 63;
  const int lr = l & 15, quad = l >> 4;
  const int wm = w >> 2, wn = w & 3;

  const floatx4 fz = {0.f, 0.f, 0.f, 0.f};
  floatx4 acc[8][4];
#pragma unroll
  for (int i = 0; i < 8; i++)
#pragma unroll
    for (int j = 0; j < 4; j++) acc[i][j] = fz;

  // staging: chunk c in [0,1024) per k-half: row=c>>2, phys=c&3,
  // global chunk gq = (c&3)^((c>>3)&3). Thread stages c = tid and 512+tid.
  const int r0 = tid >> 2;
  const int gq0 = (tid & 3) ^ ((tid >> 3) & 3);
  const half_t* aS0 = A + (long long)(m0 + r0) * lda + gq0 * 8;
  const half_t* aS1 = aS0 + (long long)128 * lda;
  const half_t* bS0 = Bt + (long long)(n0 + r0) * ldb + gq0 * 8;
  const half_t* bS1 = bS0 + (long long)128 * ldb;
  const int wso = w << 9;  // wave-uniform LDS chunk base

  // frag read: row = Rbase + lr, phys chunk = quad ^ ((lr>>1)&3)
  const int swz = (quad ^ ((lr >> 1) & 3)) << 3;
  const int aBase = wm * 4096 + lr * 32 + swz;
  const int bBase = wn * 2048 + lr * 32 + swz;
  const int NT = K >> 6;

#define SA(BUF, KH, KOFF) do { half_t* d_ = &As[(BUF) * 16384 + (KH) * 8192 + wso]; \
    gload16(aS0 + (KOFF), d_); gload16(aS1 + (KOFF), d_ + 4096); } while (0)
#define SB(BUF, KH, KOFF) do { half_t* d_ = &Bs[(BUF) * 16384 + (KH) * 8192 + wso]; \
    gload16(bS0 + (KOFF), d_); gload16(bS1 + (KOFF), d_ + 4096); } while (0)
#define LDA4(S, OFF) { const half_t* ap_ = &As[(OFF)]; \
    S##0 = *(const short8*)(ap_); S##1 = *(const short8*)(ap_ + 512); \
    S##2 = *(const short8*)(ap_ + 1024); S##3 = *(const short8*)(ap_ + 1536); }
#define LDB4(S, OFF) { const half_t* bp_ = &Bs[(OFF)]; \
    S##0 = *(const short8*)(bp_); S##1 = *(const short8*)(bp_ + 512); \
    S##2 = *(const short8*)(bp_ + 1024); S##3 = *(const short8*)(bp_ + 1536); }
#define MFMA16(I0, AS, BS) do { \
    acc[(I0) + 0][0] = __builtin_amdgcn_mfma_f32_16x16x32_f16(AS##0, BS##0, acc[(I0) + 0][0], 0, 0, 0); \
    acc[(I0) + 0][1] = __builtin_amdgcn_mfma_f32_16x16x32_f16(AS##0, BS##1, acc[(I0) + 0][1], 0, 0, 0); \
    acc[(I0) + 0][2] = __builtin_amdgcn_mfma_f32_16x16x32_f16(AS##0, BS##2, acc[(I0) + 0][2], 0, 0, 0); \
    acc[(I0) + 0][3] = __builtin_amdgcn_mfma_f32_16x16x32_f16(AS##0, BS##3, acc[(I0) + 0][3], 0, 0, 0); \
    acc[(I0) + 1][0] = __builtin_amdgcn_mfma_f32_16x16x32_f16(AS##1, BS##0, acc[(I0) + 1][0], 0, 0, 0); \
    acc[(I0) + 1][1] = __builtin_amdgcn_mfma_f32_16x16x32_f16(AS##1, BS##1, acc[(I0) + 1][1], 0, 0, 0); \
    acc[(I0) + 1][2] = __builtin_amdgcn_mfma_f32_16x16x32_f16(AS##1, BS##2, acc[(I0) + 1][2], 0, 0, 0); \
    acc[(I0) + 1][3] = __builtin_amdgcn_mfma_f32_16x16x32_f16(AS##1, BS##3, acc[(I0) + 1][3], 0, 0, 0); \
    acc[(I0) + 2][0] = __builtin_amdgcn_mfma_f32_16x16x32_f16(AS##2, BS##0, acc[(I0) + 2][0], 0, 0, 0); \
    acc[(I0) + 2][1] = __builtin_amdgcn_mfma_f32_16x16x32_f16(AS##2, BS##1, acc[(I0) + 2][1], 0, 0, 0); \
    acc[(I0) + 2][2] = __builtin_amdgcn_mfma_f32_16x16x32_f16(AS##2, BS##2, acc[(I0) + 2][2], 0, 0, 0); \
    acc[(I0) + 2][3] = __builtin_amdgcn_mfma_f32_16x16x32_f16(AS##2, BS##3, acc[(I0) + 2][3], 0, 0, 0); \
    acc[(I0) + 3][0] = __builtin_amdgcn_mfma_f32_16x16x32_f16(AS##3, BS##0, acc[(I0) + 3][0], 0, 0, 0); \
    acc[(I0) + 3][1] = __builtin_amdgcn_mfma_f32_16x16x32_f16(AS##3, BS##1, acc[(I0) + 3][1], 0, 0, 0); \
    acc[(I0) + 3][2] = __builtin_amdgcn_mfma_f32_16x16x32_f16(AS##3, BS##2, acc[(I0) + 3][2], 0, 0, 0); \
    acc[(I0) + 3][3] = __builtin_amdgcn_mfma_f32_16x16x32_f16(AS##3, BS##3, acc[(I0) + 3][3], 0, 0, 0); \
  } while (0)

  // prologue: tile0 {B-kh0,A-kh0,B-kh1,A-kh1} + tile1 {A-kh0,B-kh0};
  // VM8 confirms tile0 kh0 (first 4 loads); kh1 confirmed by t0.A's VM8.
  SB(0, 0, 0); SA(0, 0, 0); SB(0, 1, 32); SA(0, 1, 32);
  SA(1, 0, 64); SB(1, 0, 64);
  VM8();
  BAR();

  for (int t = 0; t < NT; ++t) {
    const int buf = t & 1, nbuf = buf ^ 1;
    const int ab = buf * 16384;
    const int kb = t * 64;

    // ---- Phase A: kh0, 32 MFMA; stage (t+1).kh1 ----
    {
      short8 aA0, aA1, aA2, aA3, aB0, aB1, aB2, aB3, bA0, bA1, bA2, bA3;
      LDA4(aA, ab + aBase);
      LDA4(aB, ab + aBase + 2048);
      LDB4(bA, ab + bBase);
      if (t + 1 < NT) {
        SA(nbuf, 1, kb + 96);
        SB(nbuf, 1, kb + 96);
        VM8();
      } else {
        VM0();
      }
      BAR(); LGKM0();
      __builtin_amdgcn_s_setprio(1);
      MFMA16(0, aA, bA);
      MFMA16(4, aB, bA);
      __builtin_amdgcn_s_setprio(0);
      BAR();
    }

    // ---- Phase B: kh1, 32 MFMA; stage (t+2).kh0 ----
    {
      short8 aA0, aA1, aA2, aA3, aB0, aB1, aB2, aB3, bA0, bA1, bA2, bA3;
      LDA4(aA, ab + 8192 + aBase);
      LDA4(aB, ab + 8192 + aBase + 2048);
      LDB4(bA, ab + 8192 + bBase);
      if (t + 2 < NT) {
        SA(buf, 0, kb + 128);
        SB(buf, 0, kb + 128);
        VM8();
      } else if (t + 1 < NT) {
        VM4();
      }
      BAR(); LGKM0();
      __builtin_amdgcn_s_setprio(1);
      MFMA16(0, aA, bA);
      MFMA16(4, aB, bA);
      __builtin_amdgcn_s_setprio(0);
      BAR();
    }
  }

  // epilogue (direct stores)
#pragma unroll
  for (int i = 0; i < 8; i++) {
#pragma unroll
    for (int j = 0; j < 4; j++) {
#pragma unroll
      for (int r = 0; r < 4; r++) {
        int grow = m0 + wm * 128 + i * 16 + quad * 4 + r;
        int gcol = n0 + wn * 64 + j * 16 + lr;
        float v = acc[i][j][r];
        if (MODE == EP_F32) {
          float* C = (float*)Cout + (long long)z * cBatch;
          C[(long long)grow * ldc + gcol] = v;
        } else {  // EP_QK, interleaved pair layout: row pos 2u,2u+1
          int sel = gcol >> 10;        // uniform per block (n0 multiple of 256)
          int ucol = gcol & 1023;
          half_t h = (half_t)v;
          unsigned hu = h2u(h);
          unsigned val;
          half_t* base;
          if (sel == 0) {  // Q: [qh, ql] pairs
            val = hu | ((unsigned)h2u((half_t)(v - (float)h)) << 16);
            base = (half_t*)Cout;
          } else {         // K: [kh, kh] pairs
            val = hu | (hu << 16);
            base = CoutK;
          }
          *(unsigned*)(base + (long long)grow * KCAT + 2 * ucol) = val;
        }
      }
    }
  }
#undef SA
#undef SB
#undef LDA4
#undef LDB4
#undef MFMA16
}

// ---------- softmax, in place: S row (fp32[2048]) -> P row (fp16[2048]) ----------
__global__ __launch_bounds__(256) void k_softmax(float* __restrict__ Sbuf) {
  long long row = blockIdx.x;  // 0..8191
  float* p = Sbuf + row * 2048;
  int t = threadIdx.x;
  float4 v0 = ((const float4*)p)[t];
  float4 v1 = ((const float4*)p)[t + 256];
  float m = fmaxf(fmaxf(fmaxf(v0.x, v0.y), fmaxf(v0.z, v0.w)),
                  fmaxf(fmaxf(v1.x, v1.y), fmaxf(v1.z, v1.w)));
  for (int off = 32; off; off >>= 1) m = fmaxf(m, __shfl_xor(m, off));
  __shared__ float red[8];
  int wv = t >> 6, ln = t & 63;
  if (ln == 0) red[wv] = m;
  __syncthreads();
  m = fmaxf(fmaxf(red[0], red[1]), fmaxf(red[2], red[3]));
  float e0 = __expf(v0.x - m), e1 = __expf(v0.y - m), e2 = __expf(v0.z - m), e3 = __expf(v0.w - m);
  float e4 = __expf(v1.x - m), e5 = __expf(v1.y - m), e6 = __expf(v1.z - m), e7 = __expf(v1.w - m);
  float s = ((e0 + e1) + (e2 + e3)) + ((e4 + e5) + (e6 + e7));
  for (int off = 32; off; off >>= 1) s += __shfl_xor(s, off);
  if (ln == 0) red[4 + wv] = s;
  __syncthreads();
  s = (red[4] + red[5]) + (red[6] + red[7]);
  float inv = 1.0f / s;
  uint2 w0, w1;
  w0.x = (unsigned)h2u((half_t)(e0 * inv)) | ((unsigned)h2u((half_t)(e1 * inv)) << 16);
  w0.y = (unsigned)h2u((half_t)(e2 * inv)) | ((unsigned)h2u((half_t)(e3 * inv)) << 16);
  w1.x = (unsigned)h2u((half_t)(e4 * inv)) | ((unsigned)h2u((half_t)(e5 * inv)) << 16);
  w1.y = (unsigned)h2u((half_t)(e6 * inv)) | ((unsigned)h2u((half_t)(e7 * inv)) << 16);
  ((uint2*)p)[t] = w0;
  ((uint2*)p)[t + 256] = w1;
}

// ---------- host launch ----------
extern "C" void kernel_launch(void* const* d_in, const int* in_sizes, int n_in,
                              void* d_out, int out_size, void* d_ws, size_t ws_size,
                              hipStream_t stream) {
  (void)in_sizes; (void)n_in; (void)out_size;
  if (ws_size < WS_NEED) return;  // output stays poisoned -> visible failure

  const float* X = (const float*)d_in[0];
  const float* Wq = (const float*)d_in[1];
  const float* Wk = (const float*)d_in[2];
  const float* Wv = (const float*)d_in[3];
  char* ws = (char*)d_ws;
  half_t* xcat = (half_t*)(ws + XCAT_OFF);
  half_t* wt = (half_t*)(ws + WT_OFF);
  float* Sbuf = (float*)(ws + S_OFF);
  half_t* qcat = (half_t*)(ws + QCAT_OFF);
  half_t* kcat = (half_t*)(ws + KCAT_OFF);
  half_t* vt = (half_t*)(ws + VT_OFF);
  float* out = (float*)d_out;

  // 1. split X and W (fp16)
  k_split_x<<<dim3(MX * 1024 / 256), dim3(256), 0, stream>>>(X, xcat);
  k_split_wt<<<dim3(16, 16, 3), dim3(256), 0, stream>>>(Wq, Wk, Wv, wt);

  // 2a. fused QK projection: M=8192, N=2048 (Wq|Wk), K=2048 (2-term)
  k_gemm256<EP_QK><<<dim3(8, 32, 1), dim3(512), 0, stream>>>(
      xcat, 0LL, KCAT, wt, 0LL, KCAT, qcat, 0LL, 0, KCAT, kcat);

  // 2b. V projection: M=8192, N=1024, K=1024 (1-term) -- 128^2, 4 blocks/CU
  k_gemm<EP_VT><<<dim3(8, 64, 1), dim3(256), 0, stream>>>(
      xcat, 0LL, KCAT, wt + 2 * 1024 * KCAT, 0LL, KCAT, vt, 0LL, 0, 1024, nullptr);

  // 3. scores S = Q K^T (fp16 2-term, interleaved k-layout on both sides)
  k_gemm256<EP_F32><<<dim3(8, 8, 4), dim3(512), 0, stream>>>(
      qcat, (long long)2048 * KCAT, KCAT, kcat, (long long)2048 * KCAT, KCAT,
      Sbuf, (long long)2048 * 2048, 2048, KCAT, nullptr);

  // 4. softmax in place (fp32 row -> fp16 row; row stride becomes 4096 halves)
  k_softmax<<<dim3(8192), dim3(256), 0, stream>>>(Sbuf);

  // 5. O = P V (plain fp16), fp32 out: per batch M=2048, N=1024, K=2048
  k_gemm<EP_F32><<<dim3(8, 16, 4), dim3(256), 0, stream>>>(
      (const half_t*)Sbuf, (long long)2048 * 4096, 4096,
      vt, (long long)1024 * 2048, 2048,
      out, (long long)2048 * 1024, 1024, 2048, nullptr);
}

// Round 8
// 313.889 us; speedup vs baseline: 1.3736x; 1.0035x over previous
//
#include <hip/hip_runtime.h>
#include <cstdint>
#include <cstddef>

// B=4, S=2048, D=1024, U=1024 self-attention, fp32 in/out.
// R15: k_gemm256 rebuilt for 2 blocks/CU TLP (R13/R14 postmortem: 1-block/CU
//      lockstep schedule pins MfmaUtil at 36% regardless of phase structure;
//      naive 128^2 @4 blocks/CU matches pipelined 256^2 @1 block/CU).
//      Tile 256x128, 8 waves (4m x 2n, 64x64/wave, acc[4][4]), BK=32,
//      3-buffer LDS (72 KB -> 2 blocks/CU), ONE barrier per K-tile:
//      {8 ds_reads(cur); stage t+2 -> buf (cur+2)%3; vmcnt(3); bar; lgkm0;
//       16 MFMA}. VM3 confirms S_{t+1} before BAR publishes it (S_{t+2} is
//      the newest 3). WAR: stage targets buf last read at t-1, drained by
//      t-1's lgkm0 (same discipline as R8-R14, correct for 6 rounds).
//      Grids 512 blocks (2/CU). V-proj/PV stay on 128^2 kernel.

typedef unsigned short ushort_t;
typedef _Float16 half_t;
typedef __attribute__((ext_vector_type(8))) short short8;
typedef __attribute__((ext_vector_type(4))) float floatx4;

__device__ inline unsigned short h2u(half_t h) {
  union { half_t h; unsigned short u; } v; v.h = h; return v.u;
}

// async 16B global -> LDS (DMA). LDS dest = wave-uniform base + lane*16 (HW).
__device__ __forceinline__ void gload16(const half_t* g, half_t* l) {
  __builtin_amdgcn_global_load_lds(
      (const __attribute__((address_space(1))) unsigned int*)g,
      (__attribute__((address_space(3))) unsigned int*)l, 16, 0, 0);
}

#define BAR() asm volatile("s_barrier" ::: "memory")
#define LGKM0() asm volatile("s_waitcnt lgkmcnt(0)" ::: "memory")
#define VM3() asm volatile("s_waitcnt vmcnt(3)" ::: "memory")
#define VM0() asm volatile("s_waitcnt vmcnt(0)" ::: "memory")

// ---------- constants ----------
#define MX 8192       // B*S
#define KCAT 2048     // 2*D (fp16 2-term split-concatenated K dim)

// ws byte offsets (regions reused across phases; S overwrites xcat/wt)
#define XCAT_OFF 0UL                  // half [8192][2048] = 33554432 B
#define WT_OFF   50331648UL           // half 3 x [1024][2048] = 12582912 B
#define S_OFF    0UL                  // float [4][2048][2048] = 67108864 B
#define QCAT_OFF 69206016UL           // half [8192][2048]
#define KCAT_OFF 119537664UL          // half [8192][2048]
#define VT_OFF   169869312UL          // half [4][1024][2048] = 16777216 B
#define WS_NEED  186646528UL

// XCD remap for gridDim.x == 8 (128^2 kernel): 4-wide rectangles (R12-proven,
// FETCH 135->49MB).
#define XCD_REMAP(BX, BY, BZ)                                              \
  const int fbid_ = blockIdx.x + 8 * (blockIdx.y + gridDim.y * blockIdx.z); \
  const int xj_ = fbid_ & 7, xi_ = fbid_ >> 3;                              \
  const int BX = ((xj_ & 1) << 2) | (xi_ & 3);                              \
  const int nrow_ = (xj_ >> 1) * ((gridDim.y * gridDim.z) >> 2) + (xi_ >> 2);\
  const int BY = nrow_ % gridDim.y;                                         \
  const int BZ = nrow_ / gridDim.y;

// XCD remap for gridDim.x == 16, 512 blocks: each XCD gets a 4x16 tile
// rectangle (4 B-panels resident, 16 A-panels streamed). Bijective.
#define XCD_REMAP16(BX, BY, BZ)                                             \
  const int fb_ = blockIdx.x + 16 * (blockIdx.y + gridDim.y * blockIdx.z);  \
  const int xj_ = fb_ & 7, xi_ = fb_ >> 3;                                  \
  const int BX = (xj_ & 3) * 4 + (xi_ & 3);                                 \
  const int nr_ = (xj_ >> 2) * 16 + (xi_ >> 2);                             \
  const int BY = nr_ % gridDim.y;                                           \
  const int BZ = nr_ / gridDim.y;

// ---------- K1a: split inputs X -> Xcat = [xh | xl] (fp16) ----------
__global__ __launch_bounds__(256) void k_split_x(const float* __restrict__ X,
                                                 half_t* __restrict__ xcat) {
  long long i = (long long)blockIdx.x * 256 + threadIdx.x;  // over 8192*1024
  float x = X[i];
  half_t h = (half_t)x;
  half_t lo = (half_t)(x - (float)h);
  long long row = i >> 10;
  int col = (int)(i & 1023);
  half_t* r = xcat + row * KCAT;
  r[col] = h;
  r[col + 1024] = lo;
}

// ---------- K1b: transpose W -> WT_cat = [Wh | Wh] per weight ----------
__global__ __launch_bounds__(256) void k_split_wt(const float* __restrict__ Wq,
                                                  const float* __restrict__ Wk,
                                                  const float* __restrict__ Wv,
                                                  half_t* __restrict__ wt) {
  __shared__ float tile[64][65];
  const float* W = (blockIdx.z == 0) ? Wq : ((blockIdx.z == 1) ? Wk : Wv);
  half_t* out = wt + (size_t)blockIdx.z * 1024 * KCAT;
  int d0 = blockIdx.y * 64, u0 = blockIdx.x * 64;
  int t = threadIdx.x;
  int tr = t >> 6, tc = t & 63;
  for (int r = 0; r < 64; r += 4)
    tile[r + tr][tc] = W[(size_t)(d0 + r + tr) * 1024 + (u0 + tc)];
  __syncthreads();
  for (int r = 0; r < 64; r += 4) {
    int urow = r + tr, dcol = tc;
    float x = tile[dcol][urow];  // = WT[u0+urow][d0+dcol]
    half_t h = (half_t)x;
    half_t* o = out + (size_t)(u0 + urow) * KCAT + d0;
    o[dcol] = h;
    o[dcol + 1024] = h;
  }
}

enum { EP_F32 = 0, EP_QK = 1, EP_VT = 2 };

// ---------- old 128x128 GEMM (V-proj EP_VT; PV EP_F32) ----------
template <int MODE>
__global__ __launch_bounds__(256, 4) void k_gemm(
    const half_t* __restrict__ A, long long aBatch, int lda,
    const half_t* __restrict__ Bt, long long bBatch, int ldb,
    void* __restrict__ Cout, long long cBatch, int ldc, int K,
    half_t* __restrict__ CoutK) {
  __shared__ __align__(16) half_t As[128 * 64];
  __shared__ __align__(16) half_t Bs[128 * 64];
  const int t = threadIdx.x;
  XCD_REMAP(bx, by, z);
  A += (long long)z * aBatch;
  Bt += (long long)z * bBatch;
  const int m0 = by * 128, n0 = bx * 128;

  const int w = t >> 6, l = t & 63;
  const int lr = l & 15, quad = l >> 4;
  const int wm = (w >> 1) * 64, wn = (w & 1) * 64;

  const floatx4 fz = {0.f, 0.f, 0.f, 0.f};
  floatx4 acc[4][4];
#pragma unroll
  for (int i = 0; i < 4; i++)
#pragma unroll
    for (int j = 0; j < 4; j++) acc[i][j] = fz;

  const half_t* Ap[4];
  const half_t* Bp[4];
  half_t* ldsA[4];
  half_t* ldsB[4];
#pragma unroll
  for (int s = 0; s < 4; s++) {
    int c = s * 256 + t;
    int row = c >> 3, gq = (c & 7) ^ ((c >> 3) & 7);
    Ap[s] = A + (long long)(m0 + row) * lda + gq * 8;
    Bp[s] = Bt + (long long)(n0 + row) * ldb + gq * 8;
    ldsA[s] = &As[(s * 256 + w * 64) * 8];
    ldsB[s] = &Bs[(s * 256 + w * 64) * 8];
  }

  const int p0 = quad ^ (lr & 7);
  const int p1 = (quad + 4) ^ (lr & 7);
  const int arow = (wm + lr) * 64, brow = (wn + lr) * 64;

  for (int kb = 0; kb < K; kb += 64) {
    __syncthreads();
#pragma unroll
    for (int s = 0; s < 4; s++) {
      gload16(Ap[s] + kb, ldsA[s]);
      gload16(Bp[s] + kb, ldsB[s]);
    }
    __syncthreads();
#pragma unroll
    for (int s = 0; s < 2; s++) {
      const int pp = s ? p1 : p0;
      short8 af[4], bfg[4];
#pragma unroll
      for (int j = 0; j < 4; j++) bfg[j] = *(const short8*)&Bs[brow + j * 1024 + pp * 8];
#pragma unroll
      for (int i = 0; i < 4; i++) af[i] = *(const short8*)&As[arow + i * 1024 + pp * 8];
#pragma unroll
      for (int i = 0; i < 4; i++)
#pragma unroll
        for (int j = 0; j < 4; j++)
          acc[i][j] = __builtin_amdgcn_mfma_f32_16x16x32_f16(af[i], bfg[j], acc[i][j], 0, 0, 0);
    }
  }

#pragma unroll
  for (int i = 0; i < 4; i++) {
#pragma unroll
    for (int j = 0; j < 4; j++) {
#pragma unroll
      for (int r = 0; r < 4; r++) {
        int grow = m0 + wm + i * 16 + quad * 4 + r;
        int gcol = n0 + wn + j * 16 + lr;
        float v = acc[i][j][r];
        if (MODE == EP_F32) {
          float* C = (float*)Cout + (long long)z * cBatch;
          C[(long long)grow * ldc + gcol] = v;
        } else {  // EP_VT: V^T[b][u][s] = V[b*2048+s][u]
          half_t* C = (half_t*)Cout;
          int b = grow >> 11, s = grow & 2047;
          C[((long long)b * 1024 + gcol) * 2048 + s] = (half_t)v;
        }
      }
    }
  }
}

// ---------- 256x128 GEMM, 3-buffer 1-barrier-per-tile, 2 blocks/CU ----------
// 8 waves (4m x 2n), per-wave 64x64 output = acc[4][4] frags of 16x16x32.
// LDS: A [3 buf][256 rows][32 halves] = 48 KiB, B [3][128][32] = 24 KiB.
// Per K-tile (BK=32): 8 ds_read_b128, 3 gload16 (stage t+2), vmcnt(3),
// s_barrier, lgkmcnt(0), 16 MFMA. One barrier per tile.
template <int MODE>
__global__ __launch_bounds__(512, 4) void k_gemm256(
    const half_t* __restrict__ A, long long aBatch, int lda,
    const half_t* __restrict__ Bt, long long bBatch, int ldb,
    void* __restrict__ Cout, long long cBatch, int ldc, int K,
    half_t* __restrict__ CoutK) {
  __shared__ __align__(16) half_t As[24576];  // [3][256][32]
  __shared__ __align__(16) half_t Bs[12288];  // [3][128][32]
  const int tid = threadIdx.x;
  XCD_REMAP16(bx, by, z);
  A += (long long)z * aBatch;
  Bt += (long long)z * bBatch;
  const int m0 = by * 256, n0 = bx * 128;
  const int w = tid >> 6, l = tid & 63;
  const int lr = l & 15, quad = l >> 4;
  const int wm = w >> 1, wn = w & 1;

  const floatx4 fz = {0.f, 0.f, 0.f, 0.f};
  floatx4 acc[4][4];
#pragma unroll
  for (int i = 0; i < 4; i++)
#pragma unroll
    for (int j = 0; j < 4; j++) acc[i][j] = fz;

  // staging: A chunks c in [0,1024): row=c>>2, phys=c&3, gq=(c&3)^((c>>3)&3).
  // Thread stages A chunks tid and 512+tid (2 gloads), B chunk tid (1 gload).
  const int r0 = tid >> 2;
  const int gq0 = (tid & 3) ^ ((tid >> 3) & 3);
  const half_t* aS0 = A + (long long)(m0 + r0) * lda + gq0 * 8;
  const half_t* aS1 = aS0 + (long long)128 * lda;
  const half_t* bS0 = Bt + (long long)(n0 + r0) * ldb + gq0 * 8;  // r0<128
  const int wso = w << 9;  // wave-uniform LDS chunk base (w*64 chunks * 8)

  // frag read: row = Rbase + lr (Rbase mult of 16), phys = quad^((lr>>1)&3)
  const int swz = (quad ^ ((lr >> 1) & 3)) << 3;
  const int aBase = wm * 2048 + lr * 32 + swz;  // + i*512 + buf*8192
  const int bBase = wn * 2048 + lr * 32 + swz;  // + j*512 + buf*4096
  const int NT = K >> 5;

#define SA(BUF, KOFF) do { half_t* d_ = &As[(BUF) * 8192 + wso]; \
    gload16(aS0 + (KOFF), d_); gload16(aS1 + (KOFF), d_ + 4096); } while (0)
#define SB(BUF, KOFF) do { half_t* d_ = &Bs[(BUF) * 4096 + wso]; \
    gload16(bS0 + (KOFF), d_); } while (0)
#define LDA4(S, OFF) { const half_t* ap_ = &As[(OFF)]; \
    S##0 = *(const short8*)(ap_); S##1 = *(const short8*)(ap_ + 512); \
    S##2 = *(const short8*)(ap_ + 1024); S##3 = *(const short8*)(ap_ + 1536); }
#define LDB4(S, OFF) { const half_t* bp_ = &Bs[(OFF)]; \
    S##0 = *(const short8*)(bp_); S##1 = *(const short8*)(bp_ + 512); \
    S##2 = *(const short8*)(bp_ + 1024); S##3 = *(const short8*)(bp_ + 1536); }
#define MFMA16(AS, BS) do { \
    acc[0][0] = __builtin_amdgcn_mfma_f32_16x16x32_f16(AS##0, BS##0, acc[0][0], 0, 0, 0); \
    acc[0][1] = __builtin_amdgcn_mfma_f32_16x16x32_f16(AS##0, BS##1, acc[0][1], 0, 0, 0); \
    acc[0][2] = __builtin_amdgcn_mfma_f32_16x16x32_f16(AS##0, BS##2, acc[0][2], 0, 0, 0); \
    acc[0][3] = __builtin_amdgcn_mfma_f32_16x16x32_f16(AS##0, BS##3, acc[0][3], 0, 0, 0); \
    acc[1][0] = __builtin_amdgcn_mfma_f32_16x16x32_f16(AS##1, BS##0, acc[1][0], 0, 0, 0); \
    acc[1][1] = __builtin_amdgcn_mfma_f32_16x16x32_f16(AS##1, BS##1, acc[1][1], 0, 0, 0); \
    acc[1][2] = __builtin_amdgcn_mfma_f32_16x16x32_f16(AS##1, BS##2, acc[1][2], 0, 0, 0); \
    acc[1][3] = __builtin_amdgcn_mfma_f32_16x16x32_f16(AS##1, BS##3, acc[1][3], 0, 0, 0); \
    acc[2][0] = __builtin_amdgcn_mfma_f32_16x16x32_f16(AS##2, BS##0, acc[2][0], 0, 0, 0); \
    acc[2][1] = __builtin_amdgcn_mfma_f32_16x16x32_f16(AS##2, BS##1, acc[2][1], 0, 0, 0); \
    acc[2][2] = __builtin_amdgcn_mfma_f32_16x16x32_f16(AS##2, BS##2, acc[2][2], 0, 0, 0); \
    acc[2][3] = __builtin_amdgcn_mfma_f32_16x16x32_f16(AS##2, BS##3, acc[2][3], 0, 0, 0); \
    acc[3][0] = __builtin_amdgcn_mfma_f32_16x16x32_f16(AS##3, BS##0, acc[3][0], 0, 0, 0); \
    acc[3][1] = __builtin_amdgcn_mfma_f32_16x16x32_f16(AS##3, BS##1, acc[3][1], 0, 0, 0); \
    acc[3][2] = __builtin_amdgcn_mfma_f32_16x16x32_f16(AS##3, BS##2, acc[3][2], 0, 0, 0); \
    acc[3][3] = __builtin_amdgcn_mfma_f32_16x16x32_f16(AS##3, BS##3, acc[3][3], 0, 0, 0); \
  } while (0)

  // prologue: stage tile0 (buf0) + tile1 (buf1); VM3 confirms tile0's 3.
  SA(0, 0); SB(0, 0);
  SA(1, 32); SB(1, 32);
  VM3();
  BAR();

  int cur = 0;
  for (int t = 0; t < NT; ++t) {
    short8 aA0, aA1, aA2, aA3, bA0, bA1, bA2, bA3;
    LDA4(aA, cur * 8192 + aBase);
    LDB4(bA, cur * 4096 + bBase);
    if (t + 2 < NT) {
      const int sb = (cur >= 1) ? cur - 1 : 2;  // (cur+2)%3
      SA(sb, (t + 2) * 32);
      SB(sb, (t + 2) * 32);
      VM3();  // leaves the 3 just issued; confirms S_{t+1}
    } else if (t == NT - 2) {
      VM0();  // drain S_{NT-1} for the last tile
    }
    BAR();   // publishes S_{t+1} (and this tile's data for cross-wave reads)
    LGKM0();
    __builtin_amdgcn_s_setprio(1);
    MFMA16(aA, bA);
    __builtin_amdgcn_s_setprio(0);
    cur = (cur == 2) ? 0 : cur + 1;
  }

  // epilogue (direct stores)
#pragma unroll
  for (int i = 0; i < 4; i++) {
#pragma unroll
    for (int j = 0; j < 4; j++) {
#pragma unroll
      for (int r = 0; r < 4; r++) {
        int grow = m0 + wm * 64 + i * 16 + quad * 4 + r;
        int gcol = n0 + wn * 64 + j * 16 + lr;
        float v = acc[i][j][r];
        if (MODE == EP_F32) {
          float* C = (float*)Cout + (long long)z * cBatch;
          C[(long long)grow * ldc + gcol] = v;
        } else {  // EP_QK, interleaved pair layout: row pos 2u,2u+1
          int sel = gcol >> 10;        // uniform per block (n0 multiple of 128)
          int ucol = gcol & 1023;
          half_t h = (half_t)v;
          unsigned hu = h2u(h);
          unsigned val;
          half_t* base;
          if (sel == 0) {  // Q: [qh, ql] pairs
            val = hu | ((unsigned)h2u((half_t)(v - (float)h)) << 16);
            base = (half_t*)Cout;
          } else {         // K: [kh, kh] pairs
            val = hu | (hu << 16);
            base = CoutK;
          }
          *(unsigned*)(base + (long long)grow * KCAT + 2 * ucol) = val;
        }
      }
    }
  }
#undef SA
#undef SB
#undef LDA4
#undef LDB4
#undef MFMA16
}

// ---------- softmax, in place: S row (fp32[2048]) -> P row (fp16[2048]) ----------
__global__ __launch_bounds__(256) void k_softmax(float* __restrict__ Sbuf) {
  long long row = blockIdx.x;  // 0..8191
  float* p = Sbuf + row * 2048;
  int t = threadIdx.x;
  float4 v0 = ((const float4*)p)[t];
  float4 v1 = ((const float4*)p)[t + 256];
  float m = fmaxf(fmaxf(fmaxf(v0.x, v0.y), fmaxf(v0.z, v0.w)),
                  fmaxf(fmaxf(v1.x, v1.y), fmaxf(v1.z, v1.w)));
  for (int off = 32; off; off >>= 1) m = fmaxf(m, __shfl_xor(m, off));
  __shared__ float red[8];
  int wv = t >> 6, ln = t & 63;
  if (ln == 0) red[wv] = m;
  __syncthreads();
  m = fmaxf(fmaxf(red[0], red[1]), fmaxf(red[2], red[3]));
  float e0 = __expf(v0.x - m), e1 = __expf(v0.y - m), e2 = __expf(v0.z - m), e3 = __expf(v0.w - m);
  float e4 = __expf(v1.x - m), e5 = __expf(v1.y - m), e6 = __expf(v1.z - m), e7 = __expf(v1.w - m);
  float s = ((e0 + e1) + (e2 + e3)) + ((e4 + e5) + (e6 + e7));
  for (int off = 32; off; off >>= 1) s += __shfl_xor(s, off);
  if (ln == 0) red[4 + wv] = s;
  __syncthreads();
  s = (red[4] + red[5]) + (red[6] + red[7]);
  float inv = 1.0f / s;
  uint2 w0, w1;
  w0.x = (unsigned)h2u((half_t)(e0 * inv)) | ((unsigned)h2u((half_t)(e1 * inv)) << 16);
  w0.y = (unsigned)h2u((half_t)(e2 * inv)) | ((unsigned)h2u((half_t)(e3 * inv)) << 16);
  w1.x = (unsigned)h2u((half_t)(e4 * inv)) | ((unsigned)h2u((half_t)(e5 * inv)) << 16);
  w1.y = (unsigned)h2u((half_t)(e6 * inv)) | ((unsigned)h2u((half_t)(e7 * inv)) << 16);
  ((uint2*)p)[t] = w0;
  ((uint2*)p)[t + 256] = w1;
}

// ---------- host launch ----------
extern "C" void kernel_launch(void* const* d_in, const int* in_sizes, int n_in,
                              void* d_out, int out_size, void* d_ws, size_t ws_size,
                              hipStream_t stream) {
  (void)in_sizes; (void)n_in; (void)out_size;
  if (ws_size < WS_NEED) return;  // output stays poisoned -> visible failure

  const float* X = (const float*)d_in[0];
  const float* Wq = (const float*)d_in[1];
  const float* Wk = (const float*)d_in[2];
  const float* Wv = (const float*)d_in[3];
  char* ws = (char*)d_ws;
  half_t* xcat = (half_t*)(ws + XCAT_OFF);
  half_t* wt = (half_t*)(ws + WT_OFF);
  float* Sbuf = (float*)(ws + S_OFF);
  half_t* qcat = (half_t*)(ws + QCAT_OFF);
  half_t* kcat = (half_t*)(ws + KCAT_OFF);
  half_t* vt = (half_t*)(ws + VT_OFF);
  float* out = (float*)d_out;

  // 1. split X and W (fp16)
  k_split_x<<<dim3(MX * 1024 / 256), dim3(256), 0, stream>>>(X, xcat);
  k_split_wt<<<dim3(16, 16, 3), dim3(256), 0, stream>>>(Wq, Wk, Wv, wt);

  // 2a. fused QK projection: M=8192, N=2048 (Wq|Wk), K=2048 (2-term)
  //     256x128 tiles -> (16, 32) = 512 blocks = 2/CU.
  k_gemm256<EP_QK><<<dim3(16, 32, 1), dim3(512), 0, stream>>>(
      xcat, 0LL, KCAT, wt, 0LL, KCAT, qcat, 0LL, 0, KCAT, kcat);

  // 2b. V projection: M=8192, N=1024, K=1024 (1-term) -- 128^2, 4 blocks/CU
  k_gemm<EP_VT><<<dim3(8, 64, 1), dim3(256), 0, stream>>>(
      xcat, 0LL, KCAT, wt + 2 * 1024 * KCAT, 0LL, KCAT, vt, 0LL, 0, 1024, nullptr);

  // 3. scores S = Q K^T (fp16 2-term, interleaved k-layout on both sides)
  //    per batch (16, 8) x 4 = 512 blocks = 2/CU.
  k_gemm256<EP_F32><<<dim3(16, 8, 4), dim3(512), 0, stream>>>(
      qcat, (long long)2048 * KCAT, KCAT, kcat, (long long)2048 * KCAT, KCAT,
      Sbuf, (long long)2048 * 2048, 2048, KCAT, nullptr);

  // 4. softmax in place (fp32 row -> fp16 row; row stride becomes 4096 halves)
  k_softmax<<<dim3(8192), dim3(256), 0, stream>>>(Sbuf);

  // 5. O = P V (plain fp16), fp32 out: per batch M=2048, N=1024, K=2048
  k_gemm<EP_F32><<<dim3(8, 16, 4), dim3(256), 0, stream>>>(
      (const half_t*)Sbuf, (long long)2048 * 4096, 4096,
      vt, (long long)1024 * 2048, 2048,
      out, (long long)2048 * 1024, 1024, 2048, nullptr);
}